// Round 1
// baseline (3486.917 us; speedup 1.0000x reference)
//
#include <hip/hip_runtime.h>
#include <hip/hip_bf16.h>
#include <math.h>

// ---------------------------------------------------------------------------
// BasicGNNEncoder: h = relu(NF @ Wp.T + bp); 2x { s = segsum(h[src], dst);
// agg = s @ We.T + deg*eb; h = GRU(agg, h) }.
// All GEMMs are M=100000 x N=128, K in {128,256}; epilogues fuse the GRU.
// ---------------------------------------------------------------------------

#define HID 128
#define BM 64
#define BK 32
#define AS_STRIDE 65     // odd: conflict-free scalar access, k-major
#define BS_STRIDE 132    // 128+4: float4-aligned rows

// MODE: 0=proj(relu) 1=agg(deg*bias) 2=R(sigmoid) 3=HN(plain)
//       4=N(tanh, aux1=R aux2=HN, out overwrites R) 5=OUT(z blend, aux1=n aux2=h)
template <int MODE>
__global__ __launch_bounds__(256) void gemm128(
    const float* __restrict__ A1, int lda1, int K1,
    const float* __restrict__ A2, int lda2, int K2,
    const float* __restrict__ B1, int ldb1,
    const float* __restrict__ B2, int ldb2,
    const float* __restrict__ bias1, const float* __restrict__ bias2,
    const float* __restrict__ aux1, const float* __restrict__ aux2,
    float* __restrict__ out, int M)
{
    __shared__ __align__(16) float As[BK * AS_STRIDE];
    __shared__ __align__(16) float Bs[BK * BS_STRIDE];

    const int bm  = blockIdx.x * BM;
    const int tid = threadIdx.x;
    const int tm  = tid >> 4;   // 0..15 : row group (4 rows)
    const int tn  = tid & 15;   // 0..15 : col group (8 cols)

    float acc[4][8];
#pragma unroll
    for (int r = 0; r < 4; ++r)
#pragma unroll
        for (int c = 0; c < 8; ++c) acc[r][c] = 0.f;

    const int KT = (K1 + K2) >> 5;   // 32-wide k tiles

    for (int kt = 0; kt < KT; ++kt) {
        const int k0 = kt << 5;
        const float* Ap; int lda, ka;
        const float* Bp; int ldb;
        if (k0 < K1) { Ap = A1; lda = lda1; ka = k0;      Bp = B1; ldb = ldb1; }
        else         { Ap = A2; lda = lda2; ka = k0 - K1; Bp = B2; ldb = ldb2; }

        // stage A tile: 64 rows x 32 k, k-major in LDS
#pragma unroll
        for (int i = 0; i < 8; ++i) {
            const int idx = i * 256 + tid;
            const int kk = idx & 31, mm = idx >> 5;
            const int row = bm + mm;
            As[kk * AS_STRIDE + mm] =
                (row < M) ? Ap[(size_t)row * lda + ka + kk] : 0.f;
        }
        // stage B tile: 128 rows (out cols) x 32 k, k-major in LDS
#pragma unroll
        for (int i = 0; i < 16; ++i) {
            const int idx = i * 256 + tid;
            const int kk = idx & 31, nn = idx >> 5;
            Bs[kk * BS_STRIDE + nn] = Bp[(size_t)nn * ldb + ka + kk];
        }
        __syncthreads();

#pragma unroll
        for (int kk = 0; kk < BK; ++kk) {
            const float a0 = As[kk * AS_STRIDE + tm * 4 + 0];
            const float a1 = As[kk * AS_STRIDE + tm * 4 + 1];
            const float a2 = As[kk * AS_STRIDE + tm * 4 + 2];
            const float a3 = As[kk * AS_STRIDE + tm * 4 + 3];
            const float4 b0 = *reinterpret_cast<const float4*>(&Bs[kk * BS_STRIDE + tn * 8]);
            const float4 b1 = *reinterpret_cast<const float4*>(&Bs[kk * BS_STRIDE + tn * 8 + 4]);
            const float bv[8] = {b0.x, b0.y, b0.z, b0.w, b1.x, b1.y, b1.z, b1.w};
            const float av[4] = {a0, a1, a2, a3};
#pragma unroll
            for (int r = 0; r < 4; ++r)
#pragma unroll
                for (int c = 0; c < 8; ++c)
                    acc[r][c] = fmaf(av[r], bv[c], acc[r][c]);
        }
        __syncthreads();
    }

    // epilogue
#pragma unroll
    for (int r = 0; r < 4; ++r) {
        const int i = bm + tm * 4 + r;
        if (i < M) {
#pragma unroll
            for (int c = 0; c < 8; ++c) {
                const int j = tn * 8 + c;
                const size_t ij = (size_t)i * HID + j;
                float v = acc[r][c];
                if (MODE == 0) {                       // proj + relu
                    v += bias1[j];
                    v = fmaxf(v, 0.f);
                } else if (MODE == 1) {                // agg: + deg[i]*edge_b[j]
                    v += aux1[i] * bias1[j];
                } else if (MODE == 2) {                // r gate
                    v += bias1[j] + bias2[j];
                    v = 1.f / (1.f + expf(-v));
                } else if (MODE == 3) {                // hn
                    v += bias1[j];
                } else if (MODE == 4) {                // n = tanh(inn + r*hn)
                    v = tanhf(v + bias1[j] + aux1[ij] * aux2[ij]);
                } else if (MODE == 5) {                // h' = n + z*(h-n)
                    const float z = 1.f / (1.f + expf(-(v + bias1[j] + bias2[j])));
                    const float n = aux1[ij];
                    v = n + z * (aux2[ij] - n);
                }
                out[ij] = v;
            }
        }
    }
}

// scatter-add: s[dst] += h[src], 32 threads per edge (float4 per thread)
__global__ __launch_bounds__(256) void scatter_add_kernel(
    const float* __restrict__ h, const int* __restrict__ src,
    const int* __restrict__ dst, float* __restrict__ s, int nE)
{
    const int t = blockIdx.x * 256 + threadIdx.x;
    const int e = t >> 5;
    const int lane = t & 31;
    if (e >= nE) return;
    const int si = src[e];
    const int di = dst[e];
    const float4 v = *reinterpret_cast<const float4*>(&h[(size_t)si * HID + lane * 4]);
    float* p = &s[(size_t)di * HID + lane * 4];
    atomicAdd(p + 0, v.x);
    atomicAdd(p + 1, v.y);
    atomicAdd(p + 2, v.z);
    atomicAdd(p + 3, v.w);
}

__global__ __launch_bounds__(256) void degree_kernel(
    const int* __restrict__ dst, float* __restrict__ deg, int nE)
{
    const int t = blockIdx.x * 256 + threadIdx.x;
    if (t < nE) atomicAdd(&deg[dst[t]], 1.0f);
}

extern "C" void kernel_launch(void* const* d_in, const int* in_sizes, int n_in,
                              void* d_out, int out_size, void* d_ws, size_t ws_size,
                              hipStream_t stream)
{
    const float* NF  = (const float*)d_in[0];   // [N,256]
    const int*   EI  = (const int*)  d_in[1];   // [2,E]
    const float* Wp  = (const float*)d_in[3];   // [128,256]
    const float* bp  = (const float*)d_in[4];   // [128]
    const float* EW  = (const float*)d_in[5];   // [2,1,128,128]
    const float* EB  = (const float*)d_in[6];   // [2,1,128]
    const float* WIH = (const float*)d_in[7];   // [2,384,128]
    const float* WHH = (const float*)d_in[8];   // [2,384,128]
    const float* BIH = (const float*)d_in[9];   // [2,384]
    const float* BHH = (const float*)d_in[10];  // [2,384]
    float* out = (float*)d_out;

    const int FEAT = 256;
    const int N = in_sizes[0] / FEAT;           // 100000
    const int E = in_sizes[1] / 2;              // 640000
    const size_t NH = (size_t)N * HID;

    float* ws  = (float*)d_ws;
    float* h   = ws;            // [N,128]
    float* sR  = ws + NH;       // s / R / n  (shared buffer)
    float* agg = ws + 2 * NH;   // [N,128]
    float* hn  = ws + 3 * NH;   // [N,128]
    float* deg = ws + 4 * NH;   // [N]

    const int gemmGrid = (N + BM - 1) / BM;
    const int scatGrid = (E * 32 + 255) / 256;

    // node projection + relu
    gemm128<0><<<gemmGrid, 256, 0, stream>>>(
        NF, FEAT, FEAT, nullptr, 0, 0, Wp, FEAT, nullptr, 0,
        bp, nullptr, nullptr, nullptr, h, N);

    // degrees (shared by both layers)
    hipMemsetAsync(deg, 0, N * sizeof(float), stream);
    degree_kernel<<<(E + 255) / 256, 256, 0, stream>>>(EI + E, deg, E);

    for (int l = 0; l < 2; ++l) {
        const float* We  = EW  + (size_t)l * HID * HID;
        const float* eb  = EB  + (size_t)l * HID;
        const float* wih = WIH + (size_t)l * 384 * HID;
        const float* whh = WHH + (size_t)l * 384 * HID;
        const float* bih = BIH + (size_t)l * 384;
        const float* bhh = BHH + (size_t)l * 384;
        float* outl = (l == 1) ? out : h;

        // s = segment_sum(h[src], dst)
        hipMemsetAsync(sR, 0, NH * sizeof(float), stream);
        scatter_add_kernel<<<scatGrid, 256, 0, stream>>>(h, EI, EI + E, sR, E);

        // agg = s @ We.T + deg*eb
        gemm128<1><<<gemmGrid, 256, 0, stream>>>(
            sR, HID, HID, nullptr, 0, 0, We, HID, nullptr, 0,
            eb, nullptr, deg, nullptr, agg, N);

        // R = sigmoid(agg@wih_r.T + h@whh_r.T + bih_r + bhh_r)   -> sR
        gemm128<2><<<gemmGrid, 256, 0, stream>>>(
            agg, HID, HID, h, HID, HID, wih, HID, whh, HID,
            bih, bhh, nullptr, nullptr, sR, N);

        // hn = h@whh_n.T + bhh_n
        gemm128<3><<<gemmGrid, 256, 0, stream>>>(
            h, HID, HID, nullptr, 0, 0, whh + 256 * HID, HID, nullptr, 0,
            bhh + 256, nullptr, nullptr, nullptr, hn, N);

        // n = tanh(agg@wih_n.T + bih_n + R*hn)   -> sR (overwrites R)
        gemm128<4><<<gemmGrid, 256, 0, stream>>>(
            agg, HID, HID, nullptr, 0, 0, wih + 256 * HID, HID, nullptr, 0,
            bih + 256, nullptr, sR, hn, sR, N);

        // z = sigmoid(agg@wih_z.T + h@whh_z.T + biases); h' = n + z*(h-n)
        gemm128<5><<<gemmGrid, 256, 0, stream>>>(
            agg, HID, HID, h, HID, HID, wih + 128 * HID, HID, whh + 128 * HID, HID,
            bih + 128, bhh + 128, sR, h, outl, N);
    }
}

// Round 2
// 1443.651 us; speedup vs baseline: 2.4153x; 2.4153x over previous
//
#include <hip/hip_runtime.h>
#include <hip/hip_bf16.h>
#include <math.h>

// ---------------------------------------------------------------------------
// BasicGNNEncoder: h = relu(NF @ Wp.T + bp); 2x { s = segsum(h[src], dst);
// agg = s @ We.T + deg*eb; h = GRU(agg, h) }.
// Aggregation via CSR gather (no float atomics). GEMMs: M=100000, N=128,
// K in {128,256}; epilogues fuse the GRU math.
// ---------------------------------------------------------------------------

#define HID 128
#define BM 64
#define BK 32
#define AS_STRIDE 65     // odd: conflict-free scalar access, k-major
#define BS_STRIDE 132    // 128+4: float4-aligned rows

// MODE: 0=proj(relu) 1=agg(deg*bias) 2=R(sigmoid) 3=HN(plain)
//       4=N(tanh, aux1=R aux2=HN, out overwrites R) 5=OUT(z blend, aux1=n aux2=h)
template <int MODE>
__global__ __launch_bounds__(256) void gemm128(
    const float* __restrict__ A1, int lda1, int K1,
    const float* __restrict__ A2, int lda2, int K2,
    const float* __restrict__ B1, int ldb1,
    const float* __restrict__ B2, int ldb2,
    const float* __restrict__ bias1, const float* __restrict__ bias2,
    const float* __restrict__ aux1, const float* __restrict__ aux2,
    float* __restrict__ out, int M)
{
    __shared__ __align__(16) float As[BK * AS_STRIDE];
    __shared__ __align__(16) float Bs[BK * BS_STRIDE];

    const int bm  = blockIdx.x * BM;
    const int tid = threadIdx.x;
    const int tm  = tid >> 4;   // 0..15 : row group (4 rows)
    const int tn  = tid & 15;   // 0..15 : col group (8 cols)

    float acc[4][8];
#pragma unroll
    for (int r = 0; r < 4; ++r)
#pragma unroll
        for (int c = 0; c < 8; ++c) acc[r][c] = 0.f;

    const int KT = (K1 + K2) >> 5;   // 32-wide k tiles

    for (int kt = 0; kt < KT; ++kt) {
        const int k0 = kt << 5;
        const float* Ap; int lda, ka;
        const float* Bp; int ldb;
        if (k0 < K1) { Ap = A1; lda = lda1; ka = k0;      Bp = B1; ldb = ldb1; }
        else         { Ap = A2; lda = lda2; ka = k0 - K1; Bp = B2; ldb = ldb2; }

        // stage A tile: 64 rows x 32 k, k-major in LDS
#pragma unroll
        for (int i = 0; i < 8; ++i) {
            const int idx = i * 256 + tid;
            const int kk = idx & 31, mm = idx >> 5;
            const int row = bm + mm;
            As[kk * AS_STRIDE + mm] =
                (row < M) ? Ap[(size_t)row * lda + ka + kk] : 0.f;
        }
        // stage B tile: 128 rows (out cols) x 32 k, k-major in LDS
#pragma unroll
        for (int i = 0; i < 16; ++i) {
            const int idx = i * 256 + tid;
            const int kk = idx & 31, nn = idx >> 5;
            Bs[kk * BS_STRIDE + nn] = Bp[(size_t)nn * ldb + ka + kk];
        }
        __syncthreads();

#pragma unroll
        for (int kk = 0; kk < BK; ++kk) {
            const float a0 = As[kk * AS_STRIDE + tm * 4 + 0];
            const float a1 = As[kk * AS_STRIDE + tm * 4 + 1];
            const float a2 = As[kk * AS_STRIDE + tm * 4 + 2];
            const float a3 = As[kk * AS_STRIDE + tm * 4 + 3];
            const float4 b0 = *reinterpret_cast<const float4*>(&Bs[kk * BS_STRIDE + tn * 8]);
            const float4 b1 = *reinterpret_cast<const float4*>(&Bs[kk * BS_STRIDE + tn * 8 + 4]);
            const float bv[8] = {b0.x, b0.y, b0.z, b0.w, b1.x, b1.y, b1.z, b1.w};
            const float av[4] = {a0, a1, a2, a3};
#pragma unroll
            for (int r = 0; r < 4; ++r)
#pragma unroll
                for (int c = 0; c < 8; ++c)
                    acc[r][c] = fmaf(av[r], bv[c], acc[r][c]);
        }
        __syncthreads();
    }

    // epilogue
#pragma unroll
    for (int r = 0; r < 4; ++r) {
        const int i = bm + tm * 4 + r;
        if (i < M) {
#pragma unroll
            for (int c = 0; c < 8; ++c) {
                const int j = tn * 8 + c;
                const size_t ij = (size_t)i * HID + j;
                float v = acc[r][c];
                if (MODE == 0) {                       // proj + relu
                    v += bias1[j];
                    v = fmaxf(v, 0.f);
                } else if (MODE == 1) {                // agg: + deg[i]*edge_b[j]
                    v += aux1[i] * bias1[j];
                } else if (MODE == 2) {                // r gate
                    v += bias1[j] + bias2[j];
                    v = 1.f / (1.f + expf(-v));
                } else if (MODE == 3) {                // hn
                    v += bias1[j];
                } else if (MODE == 4) {                // n = tanh(inn + r*hn)
                    v = tanhf(v + bias1[j] + aux1[ij] * aux2[ij]);
                } else if (MODE == 5) {                // h' = n + z*(h-n)
                    const float z = 1.f / (1.f + expf(-(v + bias1[j] + bias2[j])));
                    const float n = aux1[ij];
                    v = n + z * (aux2[ij] - n);
                }
                out[ij] = v;
            }
        }
    }
}

// ---------------- CSR build (int atomics only) ----------------

__global__ __launch_bounds__(256) void hist_kernel(
    const int* __restrict__ dst, int* __restrict__ degi, int E)
{
    const int t = blockIdx.x * 256 + threadIdx.x;
    if (t < E) atomicAdd(&degi[dst[t]], 1);
}

// per-block (1024 elems) reduce of degi -> bsum
__global__ __launch_bounds__(256) void reduce_kernel(
    const int* __restrict__ degi, int* __restrict__ bsum, int N)
{
    const int base = blockIdx.x * 1024;
    const int t = threadIdx.x;
    int s = 0;
#pragma unroll
    for (int k = 0; k < 4; ++k) {
        const int i = base + t * 4 + k;
        if (i < N) s += degi[i];
    }
    __shared__ int sh[256];
    sh[t] = s; __syncthreads();
    for (int off = 128; off > 0; off >>= 1) {
        if (t < off) sh[t] += sh[t + off];
        __syncthreads();
    }
    if (t == 0) bsum[blockIdx.x] = sh[0];
}

// exclusive scan of bsum (NB <= 256) -> boff; also rowptr[N] = E
__global__ __launch_bounds__(256) void scanb_kernel(
    const int* __restrict__ bsum, int* __restrict__ boff, int NB,
    int* __restrict__ rowptr, int N, int E)
{
    const int t = threadIdx.x;
    const int v = (t < NB) ? bsum[t] : 0;
    __shared__ int sh[256];
    sh[t] = v; __syncthreads();
    for (int off = 1; off < 256; off <<= 1) {
        const int x = (t >= off) ? sh[t - off] : 0;
        __syncthreads();
        sh[t] += x;
        __syncthreads();
    }
    if (t < NB) boff[t] = sh[t] - v;
    if (t == 0) rowptr[N] = E;
}

// per-block exclusive scan: rowptr/cursor/degf from degi + boff
__global__ __launch_bounds__(256) void scan_kernel(
    const int* __restrict__ degi, const int* __restrict__ boff,
    int* __restrict__ rowptr, int* __restrict__ cursor,
    float* __restrict__ degf, int N)
{
    const int base = blockIdx.x * 1024;
    const int t = threadIdx.x;
    int v[4]; int s = 0;
    const int i0 = base + t * 4;
#pragma unroll
    for (int k = 0; k < 4; ++k) {
        const int i = i0 + k;
        v[k] = (i < N) ? degi[i] : 0;
        s += v[k];
    }
    __shared__ int sh[256];
    sh[t] = s; __syncthreads();
    for (int off = 1; off < 256; off <<= 1) {
        const int x = (t >= off) ? sh[t - off] : 0;
        __syncthreads();
        sh[t] += x;
        __syncthreads();
    }
    int excl = sh[t] - s + boff[blockIdx.x];
#pragma unroll
    for (int k = 0; k < 4; ++k) {
        const int i = i0 + k;
        if (i < N) {
            rowptr[i] = excl;
            cursor[i] = excl;
            degf[i]   = (float)v[k];
            excl += v[k];
        }
    }
}

__global__ __launch_bounds__(256) void fill_kernel(
    const int* __restrict__ src, const int* __restrict__ dst,
    int* __restrict__ cursor, int* __restrict__ col, int E)
{
    const int e = blockIdx.x * 256 + threadIdx.x;
    if (e < E) {
        const int p = atomicAdd(&cursor[dst[e]], 1);
        col[p] = src[e];
    }
}

// ---------------- gather aggregation: one wave per node ----------------
__global__ __launch_bounds__(256) void gather_kernel(
    const float* __restrict__ h, const int* __restrict__ rowptr,
    const int* __restrict__ col, float* __restrict__ s, int N)
{
    const int node = blockIdx.x * 4 + (threadIdx.x >> 6);
    const int lane = threadIdx.x & 63;
    if (node >= N) return;
    const int beg = rowptr[node];
    const int end = rowptr[node + 1];
    float2 a0 = make_float2(0.f, 0.f), a1 = make_float2(0.f, 0.f);
    int j = beg;
    for (; j + 1 < end; j += 2) {
        const int c0 = col[j], c1 = col[j + 1];
        const float2 v0 = *reinterpret_cast<const float2*>(&h[(size_t)c0 * HID + lane * 2]);
        const float2 v1 = *reinterpret_cast<const float2*>(&h[(size_t)c1 * HID + lane * 2]);
        a0.x += v0.x; a0.y += v0.y;
        a1.x += v1.x; a1.y += v1.y;
    }
    if (j < end) {
        const int c = col[j];
        const float2 v = *reinterpret_cast<const float2*>(&h[(size_t)c * HID + lane * 2]);
        a0.x += v.x; a0.y += v.y;
    }
    a0.x += a1.x; a0.y += a1.y;
    *reinterpret_cast<float2*>(&s[(size_t)node * HID + lane * 2]) = a0;
}

extern "C" void kernel_launch(void* const* d_in, const int* in_sizes, int n_in,
                              void* d_out, int out_size, void* d_ws, size_t ws_size,
                              hipStream_t stream)
{
    const float* NF  = (const float*)d_in[0];   // [N,256]
    const int*   EI  = (const int*)  d_in[1];   // [2,E]
    const float* Wp  = (const float*)d_in[3];   // [128,256]
    const float* bp  = (const float*)d_in[4];   // [128]
    const float* EW  = (const float*)d_in[5];   // [2,1,128,128]
    const float* EB  = (const float*)d_in[6];   // [2,1,128]
    const float* WIH = (const float*)d_in[7];   // [2,384,128]
    const float* WHH = (const float*)d_in[8];   // [2,384,128]
    const float* BIH = (const float*)d_in[9];   // [2,384]
    const float* BHH = (const float*)d_in[10];  // [2,384]
    float* out = (float*)d_out;

    const int FEAT = 256;
    const int N = in_sizes[0] / FEAT;           // 100000
    const int E = in_sizes[1] / 2;              // 640000
    const size_t NH = (size_t)N * HID;
    const int NB = (N + 1023) / 1024;           // scan blocks (<=256)

    float* ws   = (float*)d_ws;
    float* h    = ws;            // [N,128]
    float* sR   = ws + NH;       // s / R / n  (shared buffer)
    float* agg  = ws + 2 * NH;   // [N,128]
    float* hn   = ws + 3 * NH;   // [N,128]
    float* degf = ws + 4 * NH;   // [N]
    int*   degi   = (int*)(degf + N);
    int*   rowptr = degi + N;        // [N+1]
    int*   cursor = rowptr + N + 1;  // [N]
    int*   col    = cursor + N;      // [E]
    int*   bsum   = col + E;         // [NB]
    int*   boff   = bsum + 256;      // [NB]

    const int gemmGrid = (N + BM - 1) / BM;

    // node projection + relu
    gemm128<0><<<gemmGrid, 256, 0, stream>>>(
        NF, FEAT, FEAT, nullptr, 0, 0, Wp, FEAT, nullptr, 0,
        bp, nullptr, nullptr, nullptr, h, N);

    // ---- build CSR of dst (shared by both layers) ----
    hipMemsetAsync(degi, 0, N * sizeof(int), stream);
    hist_kernel<<<(E + 255) / 256, 256, 0, stream>>>(EI + E, degi, E);
    reduce_kernel<<<NB, 256, 0, stream>>>(degi, bsum, N);
    scanb_kernel<<<1, 256, 0, stream>>>(bsum, boff, NB, rowptr, N, E);
    scan_kernel<<<NB, 256, 0, stream>>>(degi, boff, rowptr, cursor, degf, N);
    fill_kernel<<<(E + 255) / 256, 256, 0, stream>>>(EI, EI + E, cursor, col, E);

    for (int l = 0; l < 2; ++l) {
        const float* We  = EW  + (size_t)l * HID * HID;
        const float* eb  = EB  + (size_t)l * HID;
        const float* wih = WIH + (size_t)l * 384 * HID;
        const float* whh = WHH + (size_t)l * 384 * HID;
        const float* bih = BIH + (size_t)l * 384;
        const float* bhh = BHH + (size_t)l * 384;
        float* outl = (l == 1) ? out : h;

        // s = segment_sum(h[src], dst)  (gather, no atomics)
        gather_kernel<<<(N + 3) / 4, 256, 0, stream>>>(h, rowptr, col, sR, N);

        // agg = s @ We.T + deg*eb
        gemm128<1><<<gemmGrid, 256, 0, stream>>>(
            sR, HID, HID, nullptr, 0, 0, We, HID, nullptr, 0,
            eb, nullptr, degf, nullptr, agg, N);

        // R = sigmoid(agg@wih_r.T + h@whh_r.T + bih_r + bhh_r)   -> sR
        gemm128<2><<<gemmGrid, 256, 0, stream>>>(
            agg, HID, HID, h, HID, HID, wih, HID, whh, HID,
            bih, bhh, nullptr, nullptr, sR, N);

        // hn = h@whh_n.T + bhh_n
        gemm128<3><<<gemmGrid, 256, 0, stream>>>(
            h, HID, HID, nullptr, 0, 0, whh + 256 * HID, HID, nullptr, 0,
            bhh + 256, nullptr, nullptr, nullptr, hn, N);

        // n = tanh(agg@wih_n.T + bih_n + R*hn)   -> sR (overwrites R)
        gemm128<4><<<gemmGrid, 256, 0, stream>>>(
            agg, HID, HID, nullptr, 0, 0, wih + 256 * HID, HID, nullptr, 0,
            bih + 256, nullptr, sR, hn, sR, N);

        // z = sigmoid(agg@wih_z.T + h@whh_z.T + biases); h' = n + z*(h-n)
        gemm128<5><<<gemmGrid, 256, 0, stream>>>(
            agg, HID, HID, h, HID, HID, wih + 128 * HID, HID, whh + 128 * HID, HID,
            bih + 128, bhh + 128, sR, h, outl, N);
    }
}

// Round 3
// 806.928 us; speedup vs baseline: 4.3212x; 1.7891x over previous
//
#include <hip/hip_runtime.h>
#include <hip/hip_bf16.h>

// ---------------------------------------------------------------------------
// BasicGNNEncoder, MFMA bf16x3 (split hi/lo) version.
//   h = relu(NF @ Wp.T + bp)
//   2x { s = segsum(h[src], dst) [CSR gather];
//        agg = s @ We.T + deg*eb;
//        h = GRU(agg, h)  [single fused kernel: Sr,Sz,inn,hn + nonlinearity] }
// All activations stored as split bf16 pairs (hi,lo) -> fp32-quality accuracy
// with bf16 MFMA (3 products/k-step: hi*hi + hi*lo + lo*hi).
// ---------------------------------------------------------------------------

typedef unsigned int u32;
typedef unsigned short u16;
typedef __attribute__((ext_vector_type(8))) short bf16x8;   // 8 bf16 = 4 VGPR
typedef __attribute__((ext_vector_type(4))) float f32x4;

#define HID 128

__device__ __forceinline__ float u2f(u32 b){ union{u32 u; float f;} v; v.u=b; return v.f; }
__device__ __forceinline__ u32 f2u(float f){ union{u32 u; float f;} v; v.f=f; return v.u; }

// split two fp32 into packed u32 of 2 bf16 (hi = truncated top16, lo = remainder trunc)
__device__ __forceinline__ void split2(float a0, float a1, u32& hi, u32& lo){
    u32 b0 = f2u(a0), b1 = f2u(a1);
    u32 h0 = b0 & 0xffff0000u, h1 = b1 & 0xffff0000u;
    hi = (b0 >> 16) | h1;
    float l0 = a0 - u2f(h0), l1 = a1 - u2f(h1);
    lo = (f2u(l0) >> 16) | (f2u(l1) & 0xffff0000u);
}

__device__ __forceinline__ float sigm(float x){ return 1.f / (1.f + __expf(-x)); }
// tanh via 1 - 2/(e^{2x}+1): saturates to +-1 without NaN at |x| large
__device__ __forceinline__ float tanh_f(float x){ return 1.f - 2.f / (1.f + __expf(2.f * x)); }

// ---------------- weight split prep ----------------
__global__ __launch_bounds__(256) void split_kernel(
    const float* __restrict__ src, int npairs, u16* __restrict__ hi, u16* __restrict__ lo)
{
    int i = blockIdx.x * 256 + threadIdx.x;
    if (i < npairs){
        float2 a = ((const float2*)src)[i];
        u32 h, l; split2(a.x, a.y, h, l);
        ((u32*)hi)[i] = h; ((u32*)lo)[i] = l;
    }
}

// ---------------- N=128 GEMM: C = A @ W.T (+epilogue), MFMA bf16x3 ----------
// MODE 0: proj  (A = NF fp32, K=256, epi: +bias, relu)      -> out pair
// MODE 1: agg   (A = s pair,  K=128, epi: +deg[row]*bias)   -> out pair
// Block: 256 thr = 4 waves over m (BM=128, each wave 32 rows); B slice in LDS.
template<int MODE>
__global__ __launch_bounds__(256) void gemm_n128(
    const float* __restrict__ Af32,
    const u16* __restrict__ Ahi, const u16* __restrict__ Alo,
    const u16* __restrict__ Whi, const u16* __restrict__ Wlo,   // [128][K] split
    const float* __restrict__ bias, const float* __restrict__ degf,
    u16* __restrict__ Ohi, u16* __restrict__ Olo, int M)
{
    constexpr int K = (MODE == 0) ? 256 : 128;
    __shared__ __align__(16) u16 ldsB[8192];   // [hl][chunk4][row128][8] = 16KB
    const int tid = threadIdx.x, lane = tid & 63, w = tid >> 6;
    const int m0 = blockIdx.x * 128;

    f32x4 acc[2][8];
#pragma unroll
    for (int a = 0; a < 2; ++a)
#pragma unroll
        for (int b = 0; b < 8; ++b) acc[a][b] = (f32x4){0.f, 0.f, 0.f, 0.f};

    for (int ks = 0; ks < K / 32; ++ks){
        // stage B k-slice: 128 cols x 32 k, hi+lo
        for (int u = tid; u < 1024; u += 256){
            int hl = u >> 9, idx = u & 511, chunk = idx & 3, row = idx >> 2;
            const u16* srcp = hl ? Wlo : Whi;
            bf16x8 v = *(const bf16x8*)&srcp[row * K + ks * 32 + chunk * 8];
            *(bf16x8*)&ldsB[hl * 4096 + chunk * 1024 + row * 8] = v;
        }
        __syncthreads();

        bf16x8 ah[2], al[2];
#pragma unroll
        for (int mf = 0; mf < 2; ++mf){
            int row = m0 + w * 32 + mf * 16 + (lane & 15);
            row = row < M ? row : M - 1;
            if constexpr (MODE == 0){
                const float* ap = Af32 + (size_t)row * K + ks * 32 + (lane >> 4) * 8;
                float4 fa = *(const float4*)ap;
                float4 fb = *(const float4*)(ap + 4);
                union{ bf16x8 v; u32 u[4]; } H, L;
                split2(fa.x, fa.y, H.u[0], L.u[0]);
                split2(fa.z, fa.w, H.u[1], L.u[1]);
                split2(fb.x, fb.y, H.u[2], L.u[2]);
                split2(fb.z, fb.w, H.u[3], L.u[3]);
                ah[mf] = H.v; al[mf] = L.v;
            } else {
                size_t off = (size_t)row * K + ks * 32 + (lane >> 4) * 8;
                ah[mf] = *(const bf16x8*)&Ahi[off];
                al[mf] = *(const bf16x8*)&Alo[off];
            }
        }
#pragma unroll
        for (int nf = 0; nf < 8; ++nf){
            int brow = nf * 16 + (lane & 15);
            int bi = (lane >> 4) * 1024 + brow * 8;
            bf16x8 bh = *(const bf16x8*)&ldsB[bi];
            bf16x8 bl = *(const bf16x8*)&ldsB[bi + 4096];
#pragma unroll
            for (int mf = 0; mf < 2; ++mf){
                acc[mf][nf] = __builtin_amdgcn_mfma_f32_16x16x32_bf16(ah[mf], bh, acc[mf][nf], 0, 0, 0);
                acc[mf][nf] = __builtin_amdgcn_mfma_f32_16x16x32_bf16(ah[mf], bl, acc[mf][nf], 0, 0, 0);
                acc[mf][nf] = __builtin_amdgcn_mfma_f32_16x16x32_bf16(al[mf], bh, acc[mf][nf], 0, 0, 0);
            }
        }
        __syncthreads();
    }
    // epilogue: D layout col=lane&15, row=(lane>>4)*4+r  [m89-verified]
#pragma unroll
    for (int mf = 0; mf < 2; ++mf)
#pragma unroll
        for (int nf = 0; nf < 8; ++nf){
            int col = nf * 16 + (lane & 15);
#pragma unroll
            for (int r = 0; r < 4; ++r){
                int grow = m0 + w * 32 + mf * 16 + (lane >> 4) * 4 + r;
                if (grow < M){
                    float v = acc[mf][nf][r];
                    if constexpr (MODE == 0){ v += bias[col]; v = fmaxf(v, 0.f); }
                    else                    { v += degf[grow] * bias[col]; }
                    u32 b = f2u(v);
                    float lv = v - u2f(b & 0xffff0000u);
                    size_t o = (size_t)grow * HID + col;
                    Ohi[o] = (u16)(b >> 16);
                    Olo[o] = (u16)(f2u(lv) >> 16);
                }
            }
        }
}

// ---------------- fused GRU: Sr/Sz/inn/hn MFMA + nonlinearity ---------------
// Block 256 thr = 4 waves (wave g = gate plane g), BM=64 rows.
// ks 0..3: A=agg vs wih; ks 4..7: A=h vs whh. g2(inn) only first half,
// g3(hn) only second half. Epilogue exchanges gate planes via LDS (swizzled)
// and applies sigmoid/tanh/blend; writes h' (pair) or final fp32 out.
template<int LAST>
__global__ __launch_bounds__(256, 2) void gru_fused(
    const u16* __restrict__ agg_hi, const u16* __restrict__ agg_lo,
    const u16* __restrict__ h_hi,  const u16* __restrict__ h_lo,
    const u16* __restrict__ wih_hi, const u16* __restrict__ wih_lo,   // [384][128]
    const u16* __restrict__ whh_hi, const u16* __restrict__ whh_lo,
    const float* __restrict__ bih, const float* __restrict__ bhh,     // [384]
    u16* __restrict__ out_hi, u16* __restrict__ out_lo, float* __restrict__ outf,
    int M)
{
    __shared__ __align__(16) u16 lds[32768];     // 64KB: B slices / gate planes
    float* planes = (float*)lds;
    const int tid = threadIdx.x, lane = tid & 63, g = tid >> 6;
    const int m0 = blockIdx.x * 64;

    f32x4 acc[4][8];
#pragma unroll
    for (int a = 0; a < 4; ++a)
#pragma unroll
        for (int b = 0; b < 8; ++b) acc[a][b] = (f32x4){0.f, 0.f, 0.f, 0.f};

    for (int ks = 0; ks < 8; ++ks){
        const u16* Whi = (ks < 4) ? wih_hi : whh_hi;
        const u16* Wlo = (ks < 4) ? wih_lo : whh_lo;
        const int kk = (ks & 3) * 32;
        // stage 3 active gate slices (rows 0..383 of wih or whh)
        for (int u = tid; u < 1536; u += 256){
            int gi = u >> 9, idx = u & 511, chunk = idx & 3, row = idx >> 2;
            int srow = gi * 128 + row;
            int slot = (ks < 4) ? gi : (gi == 2 ? 3 : gi);
            int so = srow * HID + kk + chunk * 8;
            bf16x8 vh = *(const bf16x8*)&Whi[so];
            bf16x8 vl = *(const bf16x8*)&Wlo[so];
            int li = slot * 8192 + chunk * 1024 + row * 8;
            *(bf16x8*)&lds[li] = vh;
            *(bf16x8*)&lds[li + 4096] = vl;
        }
        __syncthreads();

        const bool active = (g < 2) || ((g == 2) == (ks < 4));
        if (active){
            const u16* Ahi = (ks < 4) ? agg_hi : h_hi;
            const u16* Alo = (ks < 4) ? agg_lo : h_lo;
            bf16x8 ah[4], al[4];
#pragma unroll
            for (int mf = 0; mf < 4; ++mf){
                int row = m0 + mf * 16 + (lane & 15);
                row = row < M ? row : M - 1;
                size_t off = (size_t)row * HID + kk + (lane >> 4) * 8;
                ah[mf] = *(const bf16x8*)&Ahi[off];
                al[mf] = *(const bf16x8*)&Alo[off];
            }
#pragma unroll
            for (int nf = 0; nf < 8; ++nf){
                int brow = nf * 16 + (lane & 15);
                int bi = g * 8192 + (lane >> 4) * 1024 + brow * 8;
                bf16x8 bh = *(const bf16x8*)&lds[bi];
                bf16x8 bl = *(const bf16x8*)&lds[bi + 4096];
#pragma unroll
                for (int mf = 0; mf < 4; ++mf){
                    acc[mf][nf] = __builtin_amdgcn_mfma_f32_16x16x32_bf16(ah[mf], bh, acc[mf][nf], 0, 0, 0);
                    acc[mf][nf] = __builtin_amdgcn_mfma_f32_16x16x32_bf16(ah[mf], bl, acc[mf][nf], 0, 0, 0);
                    acc[mf][nf] = __builtin_amdgcn_mfma_f32_16x16x32_bf16(al[mf], bh, acc[mf][nf], 0, 0, 0);
                }
            }
        }
        __syncthreads();
    }

    // epilogue in two 32-row halves (LDS planes: 4 gates x 32 x 128 f32, swizzled)
    for (int half = 0; half < 2; ++half){
#pragma unroll
        for (int mfh = 0; mfh < 2; ++mfh){
#pragma unroll
            for (int nf = 0; nf < 8; ++nf){
                int col = nf * 16 + (lane & 15);
#pragma unroll
                for (int r = 0; r < 4; ++r){
                    int lr = mfh * 16 + (lane >> 4) * 4 + r;
                    planes[g * 4096 + lr * 128 + (col ^ ((lr & 7) << 2))] = acc[half * 2 + mfh][nf][r];
                }
            }
        }
        __syncthreads();
        {
            int lr = tid & 31, cg = tid >> 5;
            int grow = m0 + half * 32 + lr;
            if (grow < M){
                int c0 = cg * 16;
                int s = (lr & 7) << 2;
                size_t base = (size_t)grow * HID + c0;
                union{ bf16x8 v; u16 e[8]; } hh0, hh1, hl0, hl1;
                hh0.v = *(const bf16x8*)&h_hi[base];
                hh1.v = *(const bf16x8*)&h_hi[base + 8];
                hl0.v = *(const bf16x8*)&h_lo[base];
                hl1.v = *(const bf16x8*)&h_lo[base + 8];
                float o[16];
#pragma unroll
                for (int i = 0; i < 16; ++i){
                    int c = c0 + i;
                    int sw = lr * 128 + (c ^ s);
                    float Sr = planes[sw];
                    float Sz = planes[4096 + sw];
                    float Si = planes[8192 + sw];
                    float Sh = planes[12288 + sw];
                    float r = sigm(Sr + bih[c] + bhh[c]);
                    float z = sigm(Sz + bih[128 + c] + bhh[128 + c]);
                    float n = tanh_f(Si + bih[256 + c] + r * (Sh + bhh[256 + c]));
                    u16 he = (i < 8) ? hh0.e[i] : hh1.e[i - 8];
                    u16 le = (i < 8) ? hl0.e[i] : hl1.e[i - 8];
                    float hv = u2f((u32)he << 16) + u2f((u32)le << 16);
                    o[i] = n + z * (hv - n);
                }
                if (LAST){
#pragma unroll
                    for (int i = 0; i < 16; i += 4)
                        *(float4*)&outf[base + i] = make_float4(o[i], o[i+1], o[i+2], o[i+3]);
                } else {
#pragma unroll
                    for (int j = 0; j < 8; ++j){
                        u32 hb, lb; split2(o[2*j], o[2*j+1], hb, lb);
                        ((u32*)out_hi)[(base >> 1) + j] = hb;
                        ((u32*)out_lo)[(base >> 1) + j] = lb;
                    }
                }
            }
        }
        __syncthreads();
    }
}

// ---------------- CSR build (int atomics only) ----------------
__global__ __launch_bounds__(256) void hist_kernel(
    const int* __restrict__ dst, int* __restrict__ degi, int E)
{
    const int t = blockIdx.x * 256 + threadIdx.x;
    if (t < E) atomicAdd(&degi[dst[t]], 1);
}

__global__ __launch_bounds__(256) void reduce_kernel(
    const int* __restrict__ degi, int* __restrict__ bsum, int N)
{
    const int base = blockIdx.x * 1024;
    const int t = threadIdx.x;
    int s = 0;
#pragma unroll
    for (int k = 0; k < 4; ++k){
        const int i = base + t * 4 + k;
        if (i < N) s += degi[i];
    }
    __shared__ int sh[256];
    sh[t] = s; __syncthreads();
    for (int off = 128; off > 0; off >>= 1){
        if (t < off) sh[t] += sh[t + off];
        __syncthreads();
    }
    if (t == 0) bsum[blockIdx.x] = sh[0];
}

__global__ __launch_bounds__(256) void scanb_kernel(
    const int* __restrict__ bsum, int* __restrict__ boff, int NB,
    int* __restrict__ rowptr, int N, int E)
{
    const int t = threadIdx.x;
    const int v = (t < NB) ? bsum[t] : 0;
    __shared__ int sh[256];
    sh[t] = v; __syncthreads();
    for (int off = 1; off < 256; off <<= 1){
        const int x = (t >= off) ? sh[t - off] : 0;
        __syncthreads();
        sh[t] += x;
        __syncthreads();
    }
    if (t < NB) boff[t] = sh[t] - v;
    if (t == 0) rowptr[N] = E;
}

__global__ __launch_bounds__(256) void scan_kernel(
    const int* __restrict__ degi, const int* __restrict__ boff,
    int* __restrict__ rowptr, int* __restrict__ cursor,
    float* __restrict__ degf, int N)
{
    const int base = blockIdx.x * 1024;
    const int t = threadIdx.x;
    int v[4]; int s = 0;
    const int i0 = base + t * 4;
#pragma unroll
    for (int k = 0; k < 4; ++k){
        const int i = i0 + k;
        v[k] = (i < N) ? degi[i] : 0;
        s += v[k];
    }
    __shared__ int sh[256];
    sh[t] = s; __syncthreads();
    for (int off = 1; off < 256; off <<= 1){
        const int x = (t >= off) ? sh[t - off] : 0;
        __syncthreads();
        sh[t] += x;
        __syncthreads();
    }
    int excl = sh[t] - s + boff[blockIdx.x];
#pragma unroll
    for (int k = 0; k < 4; ++k){
        const int i = i0 + k;
        if (i < N){
            rowptr[i] = excl;
            cursor[i] = excl;
            degf[i]   = (float)v[k];
            excl += v[k];
        }
    }
}

__global__ __launch_bounds__(256) void fill_kernel(
    const int* __restrict__ src, const int* __restrict__ dst,
    int* __restrict__ cursor, int* __restrict__ col, int E)
{
    const int e = blockIdx.x * 256 + threadIdx.x;
    if (e < E){
        const int p = atomicAdd(&cursor[dst[e]], 1);
        col[p] = src[e];
    }
}

// ---------------- gather aggregation (pair in / pair out) ----------------
__global__ __launch_bounds__(256) void gather_kernel(
    const u32* __restrict__ hhi, const u32* __restrict__ hlo,
    const int* __restrict__ rowptr, const int* __restrict__ col,
    u32* __restrict__ shi, u32* __restrict__ slo, int N)
{
    const int node = blockIdx.x * 4 + (threadIdx.x >> 6);
    const int lane = threadIdx.x & 63;
    if (node >= N) return;
    const int beg = rowptr[node], end = rowptr[node + 1];
    float a0 = 0.f, a1 = 0.f, b0 = 0.f, b1 = 0.f;
    int j = beg;
    for (; j + 1 < end; j += 2){
        int c0 = col[j], c1 = col[j + 1];
        u32 vh0 = hhi[(size_t)c0 * 64 + lane], vl0 = hlo[(size_t)c0 * 64 + lane];
        u32 vh1 = hhi[(size_t)c1 * 64 + lane], vl1 = hlo[(size_t)c1 * 64 + lane];
        a0 += u2f(vh0 << 16) + u2f(vl0 << 16);
        a1 += u2f(vh0 & 0xffff0000u) + u2f(vl0 & 0xffff0000u);
        b0 += u2f(vh1 << 16) + u2f(vl1 << 16);
        b1 += u2f(vh1 & 0xffff0000u) + u2f(vl1 & 0xffff0000u);
    }
    if (j < end){
        int c0 = col[j];
        u32 vh = hhi[(size_t)c0 * 64 + lane], vl = hlo[(size_t)c0 * 64 + lane];
        a0 += u2f(vh << 16) + u2f(vl << 16);
        a1 += u2f(vh & 0xffff0000u) + u2f(vl & 0xffff0000u);
    }
    a0 += b0; a1 += b1;
    u32 ho, lo; split2(a0, a1, ho, lo);
    shi[(size_t)node * 64 + lane] = ho;
    slo[(size_t)node * 64 + lane] = lo;
}

extern "C" void kernel_launch(void* const* d_in, const int* in_sizes, int n_in,
                              void* d_out, int out_size, void* d_ws, size_t ws_size,
                              hipStream_t stream)
{
    const float* NF  = (const float*)d_in[0];   // [N,256]
    const int*   EI  = (const int*)  d_in[1];   // [2,E]
    const float* Wp  = (const float*)d_in[3];   // [128,256]
    const float* bp  = (const float*)d_in[4];   // [128]
    const float* EW  = (const float*)d_in[5];   // [2,1,128,128]
    const float* EB  = (const float*)d_in[6];   // [2,1,128]
    const float* WIH = (const float*)d_in[7];   // [2,384,128]
    const float* WHH = (const float*)d_in[8];   // [2,384,128]
    const float* BIH = (const float*)d_in[9];   // [2,384]
    const float* BHH = (const float*)d_in[10];  // [2,384]
    float* out = (float*)d_out;

    const int FEAT = 256;
    const int N = in_sizes[0] / FEAT;           // 100000
    const int E = in_sizes[1] / 2;              // 640000
    const size_t NH = (size_t)N * HID;
    const int NB = (N + 1023) / 1024;

    // workspace layout (u16 pair activations, then fp32 deg, split weights, ints)
    u16* h_hi = (u16*)d_ws;
    u16* h_lo = h_hi + NH;
    u16* s_hi = h_lo + NH;
    u16* s_lo = s_hi + NH;
    u16* g_hi = s_lo + NH;      // agg
    u16* g_lo = g_hi + NH;
    float* degf = (float*)(g_lo + NH);
    u16* wp_hi  = (u16*)(degf + N);
    u16* wp_lo  = wp_hi + 32768;
    u16* ew_hi  = wp_lo + 32768;    // 2 layers x 16384
    u16* ew_lo  = ew_hi + 32768;
    u16* wih_hi = ew_lo + 32768;    // 2 layers x 49152
    u16* wih_lo = wih_hi + 98304;
    u16* whh_hi = wih_lo + 98304;
    u16* whh_lo = whh_hi + 98304;
    int* degi   = (int*)(whh_lo + 98304);
    int* rowptr = degi + N;
    int* cursor = rowptr + N + 1;
    int* colA   = cursor + N;
    int* bsum   = colA + E;
    int* boff   = bsum + 256;

    // split weights to bf16 hi/lo (tiny)
    split_kernel<<<64, 256, 0, stream>>>(Wp,  16384, wp_hi,  wp_lo);
    split_kernel<<<64, 256, 0, stream>>>(EW,  16384, ew_hi,  ew_lo);
    split_kernel<<<192, 256, 0, stream>>>(WIH, 49152, wih_hi, wih_lo);
    split_kernel<<<192, 256, 0, stream>>>(WHH, 49152, whh_hi, whh_lo);

    const int g128 = (N + 127) / 128;
    // h = relu(NF @ Wp.T + bp)
    gemm_n128<0><<<g128, 256, 0, stream>>>(NF, nullptr, nullptr, wp_hi, wp_lo,
                                           bp, nullptr, h_hi, h_lo, N);

    // CSR of dst (shared by both layers)
    hipMemsetAsync(degi, 0, N * sizeof(int), stream);
    hist_kernel<<<(E + 255) / 256, 256, 0, stream>>>(EI + E, degi, E);
    reduce_kernel<<<NB, 256, 0, stream>>>(degi, bsum, N);
    scanb_kernel<<<1, 256, 0, stream>>>(bsum, boff, NB, rowptr, N, E);
    scan_kernel<<<NB, 256, 0, stream>>>(degi, boff, rowptr, cursor, degf, N);
    fill_kernel<<<(E + 255) / 256, 256, 0, stream>>>(EI, EI + E, cursor, colA, E);

    for (int l = 0; l < 2; ++l){
        gather_kernel<<<(N + 3) / 4, 256, 0, stream>>>(
            (const u32*)h_hi, (const u32*)h_lo, rowptr, colA,
            (u32*)s_hi, (u32*)s_lo, N);
        gemm_n128<1><<<g128, 256, 0, stream>>>(
            nullptr, s_hi, s_lo, ew_hi + l * 16384, ew_lo + l * 16384,
            EB + l * HID, degf, g_hi, g_lo, N);
        if (l == 0)
            gru_fused<0><<<(N + 63) / 64, 256, 0, stream>>>(
                g_hi, g_lo, h_hi, h_lo,
                wih_hi + l * 49152, wih_lo + l * 49152,
                whh_hi + l * 49152, whh_lo + l * 49152,
                BIH + l * 384, BHH + l * 384,
                h_hi, h_lo, nullptr, N);   // in-place h update (row-local)
        else
            gru_fused<1><<<(N + 63) / 64, 256, 0, stream>>>(
                g_hi, g_lo, h_hi, h_lo,
                wih_hi + l * 49152, wih_lo + l * 49152,
                whh_hi + l * 49152, whh_lo + l * 49152,
                BIH + l * 384, BHH + l * 384,
                nullptr, nullptr, out, N);
    }
}

// Round 4
// 800.256 us; speedup vs baseline: 4.3573x; 1.0083x over previous
//
#include <hip/hip_runtime.h>
#include <hip/hip_bf16.h>

// ---------------------------------------------------------------------------
// BasicGNNEncoder, MFMA bf16x3 (split hi/lo), agg-GEMM folded into GRU.
//   h = relu(NF @ Wp.T + bp)
//   Wc_g = wih_g @ We ; ebg_g = wih_g @ eb      (per layer, on device)
//   2x { s = segsum(h[src], dst) [CSR gather];
//        gates = s@Wc.T + deg*ebg + h@whh.T + biases ; h = GRU blend }
// Activations stored as split bf16 pairs (hi,lo): fp32-quality via 3 MFMA
// products per k-step (hi*hi + hi*lo + lo*hi).
// ---------------------------------------------------------------------------

typedef unsigned int u32;
typedef unsigned short u16;
typedef __attribute__((ext_vector_type(8))) short bf16x8;   // 8 bf16 = 4 VGPR
typedef __attribute__((ext_vector_type(4))) float f32x4;

#define HID 128

__device__ __forceinline__ float u2f(u32 b){ union{u32 u; float f;} v; v.u=b; return v.f; }
__device__ __forceinline__ u32 f2u(float f){ union{u32 u; float f;} v; v.f=f; return v.u; }

__device__ __forceinline__ void split2(float a0, float a1, u32& hi, u32& lo){
    u32 b0 = f2u(a0), b1 = f2u(a1);
    u32 h0 = b0 & 0xffff0000u, h1 = b1 & 0xffff0000u;
    hi = (b0 >> 16) | h1;
    float l0 = a0 - u2f(h0), l1 = a1 - u2f(h1);
    lo = (f2u(l0) >> 16) | (f2u(l1) & 0xffff0000u);
}

__device__ __forceinline__ float sigm(float x){ return 1.f / (1.f + __expf(-x)); }
__device__ __forceinline__ float tanh_f(float x){ return 1.f - 2.f / (1.f + __expf(2.f * x)); }

// ---------------- weight split prep ----------------
__global__ __launch_bounds__(256) void split_kernel(
    const float* __restrict__ src, int npairs, u16* __restrict__ hi, u16* __restrict__ lo)
{
    int i = blockIdx.x * 256 + threadIdx.x;
    if (i < npairs){
        float2 a = ((const float2*)src)[i];
        u32 h, l; split2(a.x, a.y, h, l);
        ((u32*)hi)[i] = h; ((u32*)lo)[i] = l;
    }
}

// ---------------- Wc = wih_g @ We, ebg = wih_g @ eb  (block = (l,g)) -------
__global__ __launch_bounds__(256) void wcombine_kernel(
    const float* __restrict__ WIH, const float* __restrict__ EW,
    const float* __restrict__ EB,
    u16* __restrict__ wc_hi, u16* __restrict__ wc_lo, float* __restrict__ ebg)
{
    __shared__ float WeL[16384];                 // We[l]: [128][128] f32, 64KB
    const int l = blockIdx.x / 3, g = blockIdx.x % 3;
    const int t = threadIdx.x;
    for (int u = t; u < 4096; u += 256)
        ((float4*)WeL)[u] = ((const float4*)(EW + (size_t)l * 16384))[u];
    __syncthreads();

    const int r = t >> 1, jh = (t & 1) * 64;
    const float* wr = WIH + ((size_t)l * 384 + g * 128 + r) * 128;
    float a[64];
#pragma unroll
    for (int j = 0; j < 64; ++j) a[j] = 0.f;
    for (int k = 0; k < 128; ++k){
        const float wv = wr[k];
        const float4* wel = (const float4*)(WeL + k * 128 + jh);
#pragma unroll
        for (int jj = 0; jj < 16; ++jj){
            float4 v = wel[jj];
            a[jj*4+0] = fmaf(wv, v.x, a[jj*4+0]);
            a[jj*4+1] = fmaf(wv, v.y, a[jj*4+1]);
            a[jj*4+2] = fmaf(wv, v.z, a[jj*4+2]);
            a[jj*4+3] = fmaf(wv, v.w, a[jj*4+3]);
        }
    }
    const size_t base = ((size_t)(l * 3 + g) * 16384 + r * 128 + jh);
#pragma unroll
    for (int j = 0; j < 64; j += 2){
        u32 hb, lb; split2(a[j], a[j+1], hb, lb);
        ((u32*)wc_hi)[(base + j) >> 1] = hb;
        ((u32*)wc_lo)[(base + j) >> 1] = lb;
    }
    if (t < 128){
        const float* wr2 = WIH + ((size_t)l * 384 + g * 128 + t) * 128;
        const float* eb = EB + (size_t)l * 128;
        float s = 0.f;
        for (int k = 0; k < 128; ++k) s = fmaf(wr2[k], eb[k], s);
        ebg[(l * 3 + g) * 128 + t] = s;
    }
}

// ---------------- proj: h = relu(NF @ Wp.T + bp), pair out -----------------
__global__ __launch_bounds__(256) void proj_kernel(
    const float* __restrict__ A,
    const u16* __restrict__ Whi, const u16* __restrict__ Wlo,   // [128][256] split
    const float* __restrict__ bias,
    u16* __restrict__ Ohi, u16* __restrict__ Olo, int M)
{
    constexpr int K = 256;
    __shared__ __align__(16) u16 ldsB[8192];   // [hl][chunk4][row128][8] = 16KB
    const int tid = threadIdx.x, lane = tid & 63, w = tid >> 6;
    const int m0 = blockIdx.x * 128;

    f32x4 acc[2][8];
#pragma unroll
    for (int a = 0; a < 2; ++a)
#pragma unroll
        for (int b = 0; b < 8; ++b) acc[a][b] = (f32x4){0.f, 0.f, 0.f, 0.f};

    for (int ks = 0; ks < K / 32; ++ks){
        for (int u = tid; u < 1024; u += 256){
            int hl = u >> 9, idx = u & 511, chunk = idx & 3, row = idx >> 2;
            const u16* srcp = hl ? Wlo : Whi;
            bf16x8 v = *(const bf16x8*)&srcp[row * K + ks * 32 + chunk * 8];
            *(bf16x8*)&ldsB[hl * 4096 + chunk * 1024 + row * 8] = v;
        }
        __syncthreads();

        bf16x8 ah[2], al[2];
#pragma unroll
        for (int mf = 0; mf < 2; ++mf){
            int row = m0 + w * 32 + mf * 16 + (lane & 15);
            row = row < M ? row : M - 1;
            const float* ap = A + (size_t)row * K + ks * 32 + (lane >> 4) * 8;
            float4 fa = *(const float4*)ap;
            float4 fb = *(const float4*)(ap + 4);
            union{ bf16x8 v; u32 u[4]; } H, L;
            split2(fa.x, fa.y, H.u[0], L.u[0]);
            split2(fa.z, fa.w, H.u[1], L.u[1]);
            split2(fb.x, fb.y, H.u[2], L.u[2]);
            split2(fb.z, fb.w, H.u[3], L.u[3]);
            ah[mf] = H.v; al[mf] = L.v;
        }
#pragma unroll
        for (int nf = 0; nf < 8; ++nf){
            int bi = (lane >> 4) * 1024 + (nf * 16 + (lane & 15)) * 8;
            bf16x8 bh = *(const bf16x8*)&ldsB[bi];
            bf16x8 bl = *(const bf16x8*)&ldsB[bi + 4096];
#pragma unroll
            for (int mf = 0; mf < 2; ++mf){
                acc[mf][nf] = __builtin_amdgcn_mfma_f32_16x16x32_bf16(ah[mf], bh, acc[mf][nf], 0, 0, 0);
                acc[mf][nf] = __builtin_amdgcn_mfma_f32_16x16x32_bf16(ah[mf], bl, acc[mf][nf], 0, 0, 0);
                acc[mf][nf] = __builtin_amdgcn_mfma_f32_16x16x32_bf16(al[mf], bh, acc[mf][nf], 0, 0, 0);
            }
        }
        __syncthreads();
    }
#pragma unroll
    for (int mf = 0; mf < 2; ++mf)
#pragma unroll
        for (int nf = 0; nf < 8; ++nf){
            int col = nf * 16 + (lane & 15);
#pragma unroll
            for (int r = 0; r < 4; ++r){
                int grow = m0 + w * 32 + mf * 16 + (lane >> 4) * 4 + r;
                if (grow < M){
                    float v = acc[mf][nf][r] + bias[col];
                    v = fmaxf(v, 0.f);
                    u32 b = f2u(v);
                    float lv = v - u2f(b & 0xffff0000u);
                    size_t o = (size_t)grow * HID + col;
                    Ohi[o] = (u16)(b >> 16);
                    Olo[o] = (u16)(f2u(lv) >> 16);
                }
            }
        }
}

// ---------------- fused GRU: all 4 gate planes per wave --------------------
// Block 256 thr = 4 waves; wave w owns rows m0 + w*16 .. +15 (BM=64).
// Half A (ks 0..3): A=s, B=Wc (3 gate planes)  -> accR, accZ, accI
// Half B (ks 4..7): A=h, B=whh (3 gate planes) -> accR, accZ, accH
// Epilogue fully in registers (no LDS exchange).
#define RUN_HALF(AHI, ALO, WHI, WLO, ACC2)                                        \
  for (int ks = 0; ks < 4; ++ks){                                                 \
    const int kk = ks * 32;                                                       \
    for (int u = tid; u < 3072; u += 256){                                        \
      const int ph = u >> 9, idx = u & 511;                                       \
      const int chunk = idx & 3, row = idx >> 2;                                  \
      const int p = ph >> 1;                                                      \
      const u16* Sp = (ph & 1) ? (WLO) : (WHI);                                   \
      bf16x8 v = *(const bf16x8*)&Sp[(p * 128 + row) * 128 + kk + chunk * 8];     \
      *(bf16x8*)&lds[ph * 4096 + chunk * 1024 + row * 8] = v;                     \
    }                                                                             \
    __syncthreads();                                                              \
    {                                                                             \
      const size_t aoff = arowoff + kk;                                           \
      bf16x8 ah = *(const bf16x8*)&(AHI)[aoff];                                   \
      bf16x8 al = *(const bf16x8*)&(ALO)[aoff];                                   \
      _Pragma("unroll")                                                           \
      for (int nf = 0; nf < 8; ++nf){                                             \
        const int bi = bibase + nf * 128;                                         \
        bf16x8 b0h = *(const bf16x8*)&lds[bi];                                    \
        bf16x8 b0l = *(const bf16x8*)&lds[bi + 4096];                             \
        accR[nf] = __builtin_amdgcn_mfma_f32_16x16x32_bf16(ah, b0h, accR[nf],0,0,0); \
        accR[nf] = __builtin_amdgcn_mfma_f32_16x16x32_bf16(ah, b0l, accR[nf],0,0,0); \
        accR[nf] = __builtin_amdgcn_mfma_f32_16x16x32_bf16(al, b0h, accR[nf],0,0,0); \
        bf16x8 b1h = *(const bf16x8*)&lds[bi + 8192];                             \
        bf16x8 b1l = *(const bf16x8*)&lds[bi + 12288];                            \
        accZ[nf] = __builtin_amdgcn_mfma_f32_16x16x32_bf16(ah, b1h, accZ[nf],0,0,0); \
        accZ[nf] = __builtin_amdgcn_mfma_f32_16x16x32_bf16(ah, b1l, accZ[nf],0,0,0); \
        accZ[nf] = __builtin_amdgcn_mfma_f32_16x16x32_bf16(al, b1h, accZ[nf],0,0,0); \
        bf16x8 b2h = *(const bf16x8*)&lds[bi + 16384];                            \
        bf16x8 b2l = *(const bf16x8*)&lds[bi + 20480];                            \
        ACC2[nf] = __builtin_amdgcn_mfma_f32_16x16x32_bf16(ah, b2h, ACC2[nf],0,0,0); \
        ACC2[nf] = __builtin_amdgcn_mfma_f32_16x16x32_bf16(ah, b2l, ACC2[nf],0,0,0); \
        ACC2[nf] = __builtin_amdgcn_mfma_f32_16x16x32_bf16(al, b2h, ACC2[nf],0,0,0); \
      }                                                                           \
    }                                                                             \
    __syncthreads();                                                              \
  }

template<int LAST>
__global__ __launch_bounds__(256) void gru_fused(
    const u16* __restrict__ s_hi,  const u16* __restrict__ s_lo,
    const u16* __restrict__ h_hi,  const u16* __restrict__ h_lo,
    const u16* __restrict__ wc_hi, const u16* __restrict__ wc_lo,    // [3][128][128]
    const u16* __restrict__ whh_hi,const u16* __restrict__ whh_lo,   // [384][128]
    const float* __restrict__ ebg,                                   // [3][128]
    const float* __restrict__ bih, const float* __restrict__ bhh,    // [384]
    const float* __restrict__ degf,
    u16* __restrict__ out_hi, u16* __restrict__ out_lo, float* __restrict__ outf,
    int M)
{
    __shared__ __align__(16) u16 lds[24576];    // 48KB: 3 planes x (hi,lo) x 128x32
    const int tid = threadIdx.x, lane = tid & 63, w = tid >> 6;
    const int m0 = blockIdx.x * 64;
    const int rbase = m0 + w * 16;

    f32x4 accR[8], accZ[8], accI[8], accH[8];
#pragma unroll
    for (int b = 0; b < 8; ++b){
        accR[b] = (f32x4){0.f,0.f,0.f,0.f}; accZ[b] = (f32x4){0.f,0.f,0.f,0.f};
        accI[b] = (f32x4){0.f,0.f,0.f,0.f}; accH[b] = (f32x4){0.f,0.f,0.f,0.f};
    }

    int arow = rbase + (lane & 15); arow = arow < M ? arow : M - 1;
    const size_t arowoff = (size_t)arow * HID + (lane >> 4) * 8;
    const int bibase = (lane >> 4) * 1024 + (lane & 15) * 8;

    RUN_HALF(s_hi, s_lo, wc_hi, wc_lo, accI)
    RUN_HALF(h_hi, h_lo, whh_hi, whh_lo, accH)

    // epilogue: registers only
    const int colb = lane & 15, rq = lane >> 4;
    float dg[4];
#pragma unroll
    for (int r = 0; r < 4; ++r){
        int row = rbase + rq * 4 + r;
        dg[r] = (row < M) ? degf[row] : 0.f;
    }
#pragma unroll
    for (int nf = 0; nf < 8; ++nf){
        const int c = nf * 16 + colb;
        const float br  = bih[c] + bhh[c];
        const float bz  = bih[128 + c] + bhh[128 + c];
        const float bin = bih[256 + c];
        const float bhn = bhh[256 + c];
        const float er = ebg[c], ez = ebg[128 + c], en = ebg[256 + c];
#pragma unroll
        for (int r = 0; r < 4; ++r){
            const int row = rbase + rq * 4 + r;
            if (row < M){
                const size_t o = (size_t)row * HID + c;
                const float hv = u2f((u32)h_hi[o] << 16) + u2f((u32)h_lo[o] << 16);
                const float rg = sigm(accR[nf][r] + dg[r] * er + br);
                const float zg = sigm(accZ[nf][r] + dg[r] * ez + bz);
                const float nn = tanh_f(accI[nf][r] + dg[r] * en + bin + rg * (accH[nf][r] + bhn));
                const float ov = nn + zg * (hv - nn);
                if (LAST) outf[o] = ov;
                else {
                    u32 b = f2u(ov);
                    out_hi[o] = (u16)(b >> 16);
                    out_lo[o] = (u16)(f2u(ov - u2f(b & 0xffff0000u)) >> 16);
                }
            }
        }
    }
}

// ---------------- CSR build (int atomics only) ----------------
__global__ __launch_bounds__(256) void hist_kernel(
    const int* __restrict__ dst, int* __restrict__ degi, int E)
{
    const int t = blockIdx.x * 256 + threadIdx.x;
    if (t < E) atomicAdd(&degi[dst[t]], 1);
}

__global__ __launch_bounds__(256) void reduce_kernel(
    const int* __restrict__ degi, int* __restrict__ bsum, int N)
{
    const int base = blockIdx.x * 1024;
    const int t = threadIdx.x;
    int s = 0;
#pragma unroll
    for (int k = 0; k < 4; ++k){
        const int i = base + t * 4 + k;
        if (i < N) s += degi[i];
    }
    __shared__ int sh[256];
    sh[t] = s; __syncthreads();
    for (int off = 128; off > 0; off >>= 1){
        if (t < off) sh[t] += sh[t + off];
        __syncthreads();
    }
    if (t == 0) bsum[blockIdx.x] = sh[0];
}

__global__ __launch_bounds__(256) void scanb_kernel(
    const int* __restrict__ bsum, int* __restrict__ boff, int NB,
    int* __restrict__ rowptr, int N, int E)
{
    const int t = threadIdx.x;
    const int v = (t < NB) ? bsum[t] : 0;
    __shared__ int sh[256];
    sh[t] = v; __syncthreads();
    for (int off = 1; off < 256; off <<= 1){
        const int x = (t >= off) ? sh[t - off] : 0;
        __syncthreads();
        sh[t] += x;
        __syncthreads();
    }
    if (t < NB) boff[t] = sh[t] - v;
    if (t == 0) rowptr[N] = E;
}

__global__ __launch_bounds__(256) void scan_kernel(
    const int* __restrict__ degi, const int* __restrict__ boff,
    int* __restrict__ rowptr, int* __restrict__ cursor,
    float* __restrict__ degf, int N)
{
    const int base = blockIdx.x * 1024;
    const int t = threadIdx.x;
    int v[4]; int s = 0;
    const int i0 = base + t * 4;
#pragma unroll
    for (int k = 0; k < 4; ++k){
        const int i = i0 + k;
        v[k] = (i < N) ? degi[i] : 0;
        s += v[k];
    }
    __shared__ int sh[256];
    sh[t] = s; __syncthreads();
    for (int off = 1; off < 256; off <<= 1){
        const int x = (t >= off) ? sh[t - off] : 0;
        __syncthreads();
        sh[t] += x;
        __syncthreads();
    }
    int excl = sh[t] - s + boff[blockIdx.x];
#pragma unroll
    for (int k = 0; k < 4; ++k){
        const int i = i0 + k;
        if (i < N){
            rowptr[i] = excl;
            cursor[i] = excl;
            degf[i]   = (float)v[k];
            excl += v[k];
        }
    }
}

__global__ __launch_bounds__(256) void fill_kernel(
    const int* __restrict__ src, const int* __restrict__ dst,
    int* __restrict__ cursor, int* __restrict__ col, int E)
{
    const int e = blockIdx.x * 256 + threadIdx.x;
    if (e < E){
        const int p = atomicAdd(&cursor[dst[e]], 1);
        col[p] = src[e];
    }
}

// ---------------- gather aggregation (pair in / pair out) ----------------
__global__ __launch_bounds__(256) void gather_kernel(
    const u32* __restrict__ hhi, const u32* __restrict__ hlo,
    const int* __restrict__ rowptr, const int* __restrict__ col,
    u32* __restrict__ shi, u32* __restrict__ slo, int N)
{
    const int node = blockIdx.x * 4 + (threadIdx.x >> 6);
    const int lane = threadIdx.x & 63;
    if (node >= N) return;
    const int beg = rowptr[node], end = rowptr[node + 1];
    float a0 = 0.f, a1 = 0.f, b0 = 0.f, b1 = 0.f;
    int j = beg;
    for (; j + 1 < end; j += 2){
        int c0 = col[j], c1 = col[j + 1];
        u32 vh0 = hhi[(size_t)c0 * 64 + lane], vl0 = hlo[(size_t)c0 * 64 + lane];
        u32 vh1 = hhi[(size_t)c1 * 64 + lane], vl1 = hlo[(size_t)c1 * 64 + lane];
        a0 += u2f(vh0 << 16) + u2f(vl0 << 16);
        a1 += u2f(vh0 & 0xffff0000u) + u2f(vl0 & 0xffff0000u);
        b0 += u2f(vh1 << 16) + u2f(vl1 << 16);
        b1 += u2f(vh1 & 0xffff0000u) + u2f(vl1 & 0xffff0000u);
    }
    if (j < end){
        int c0 = col[j];
        u32 vh = hhi[(size_t)c0 * 64 + lane], vl = hlo[(size_t)c0 * 64 + lane];
        a0 += u2f(vh << 16) + u2f(vl << 16);
        a1 += u2f(vh & 0xffff0000u) + u2f(vl & 0xffff0000u);
    }
    a0 += b0; a1 += b1;
    u32 ho, lo; split2(a0, a1, ho, lo);
    shi[(size_t)node * 64 + lane] = ho;
    slo[(size_t)node * 64 + lane] = lo;
}

extern "C" void kernel_launch(void* const* d_in, const int* in_sizes, int n_in,
                              void* d_out, int out_size, void* d_ws, size_t ws_size,
                              hipStream_t stream)
{
    const float* NF  = (const float*)d_in[0];   // [N,256]
    const int*   EI  = (const int*)  d_in[1];   // [2,E]
    const float* Wp  = (const float*)d_in[3];   // [128,256]
    const float* bp  = (const float*)d_in[4];   // [128]
    const float* EW  = (const float*)d_in[5];   // [2,1,128,128]
    const float* EB  = (const float*)d_in[6];   // [2,1,128]
    const float* WIH = (const float*)d_in[7];   // [2,384,128]
    const float* WHH = (const float*)d_in[8];   // [2,384,128]
    const float* BIH = (const float*)d_in[9];   // [2,384]
    const float* BHH = (const float*)d_in[10];  // [2,384]
    float* out = (float*)d_out;

    const int FEAT = 256;
    const int N = in_sizes[0] / FEAT;           // 100000
    const int E = in_sizes[1] / 2;              // 640000
    const size_t NH = (size_t)N * HID;
    const int NB = (N + 1023) / 1024;

    u16* h_hi = (u16*)d_ws;
    u16* h_lo = h_hi + NH;
    u16* s_hi = h_lo + NH;
    u16* s_lo = s_hi + NH;
    float* degf = (float*)(s_lo + NH);
    u16* wp_hi  = (u16*)(degf + N);
    u16* wp_lo  = wp_hi + 32768;
    u16* whh_hi = wp_lo + 32768;    // 2 layers x 49152
    u16* whh_lo = whh_hi + 98304;
    u16* wc_hi  = whh_lo + 98304;   // 2 layers x 3 x 16384
    u16* wc_lo  = wc_hi + 98304;
    float* ebg  = (float*)(wc_lo + 98304);   // 2 x 384
    int* degi   = (int*)(ebg + 768);
    int* rowptr = degi + N;
    int* cursor = rowptr + N + 1;
    int* colA   = cursor + N;
    int* bsum   = colA + E;
    int* boff   = bsum + 256;

    // weight prep
    split_kernel<<<64, 256, 0, stream>>>(Wp, 16384, wp_hi, wp_lo);
    split_kernel<<<192, 256, 0, stream>>>(WHH, 49152, whh_hi, whh_lo);
    wcombine_kernel<<<6, 256, 0, stream>>>(WIH, EW, EB, wc_hi, wc_lo, ebg);

    // h = relu(NF @ Wp.T + bp)
    proj_kernel<<<(N + 127) / 128, 256, 0, stream>>>(NF, wp_hi, wp_lo, bp, h_hi, h_lo, N);

    // CSR of dst (shared by both layers)
    hipMemsetAsync(degi, 0, N * sizeof(int), stream);
    hist_kernel<<<(E + 255) / 256, 256, 0, stream>>>(EI + E, degi, E);
    reduce_kernel<<<NB, 256, 0, stream>>>(degi, bsum, N);
    scanb_kernel<<<1, 256, 0, stream>>>(bsum, boff, NB, rowptr, N, E);
    scan_kernel<<<NB, 256, 0, stream>>>(degi, boff, rowptr, cursor, degf, N);
    fill_kernel<<<(E + 255) / 256, 256, 0, stream>>>(EI, EI + E, cursor, colA, E);

    for (int l = 0; l < 2; ++l){
        gather_kernel<<<(N + 3) / 4, 256, 0, stream>>>(
            (const u32*)h_hi, (const u32*)h_lo, rowptr, colA,
            (u32*)s_hi, (u32*)s_lo, N);
        if (l == 0)
            gru_fused<0><<<(N + 63) / 64, 256, 0, stream>>>(
                s_hi, s_lo, h_hi, h_lo,
                wc_hi + l * 49152, wc_lo + l * 49152,
                whh_hi + l * 49152, whh_lo + l * 49152,
                ebg + l * 384, BIH + l * 384, BHH + l * 384, degf,
                h_hi, h_lo, nullptr, N);
        else
            gru_fused<1><<<(N + 63) / 64, 256, 0, stream>>>(
                s_hi, s_lo, h_hi, h_lo,
                wc_hi + l * 49152, wc_lo + l * 49152,
                whh_hi + l * 49152, whh_lo + l * 49152,
                ebg + l * 384, BIH + l * 384, BHH + l * 384, degf,
                nullptr, nullptr, out, N);
    }
}

// Round 5
// 745.495 us; speedup vs baseline: 4.6773x; 1.0735x over previous
//
#include <hip/hip_runtime.h>
#include <hip/hip_bf16.h>

// ---------------------------------------------------------------------------
// BasicGNNEncoder, MFMA bf16x3 (split hi/lo), agg-GEMM folded into GRU.
//   h = relu(NF @ Wp.T + bp)
//   Wc_g = wih_g @ We ; ebg_g = wih_g @ eb      (per layer, on device)
//   2x { s = segsum(h[src], dst) [CSR gather];
//        gates = s@Wc.T + deg*ebg + h@whh.T + biases ; h = GRU blend }
// gru_fused: wave-per-plane (R,Z K=256 concat; I on s; H on h), mt=4,
// global_load_lds staging, plane exchange via padded LDS. 
// ---------------------------------------------------------------------------

typedef unsigned int u32;
typedef unsigned short u16;
typedef __attribute__((ext_vector_type(8))) short bf16x8;   // 8 bf16 = 4 VGPR
typedef __attribute__((ext_vector_type(4))) float f32x4;

#define HID 128

__device__ __forceinline__ float u2f(u32 b){ union{u32 u; float f;} v; v.u=b; return v.f; }
__device__ __forceinline__ u32 f2u(float f){ union{u32 u; float f;} v; v.f=f; return v.u; }

__device__ __forceinline__ void split2(float a0, float a1, u32& hi, u32& lo){
    u32 b0 = f2u(a0), b1 = f2u(a1);
    u32 h0 = b0 & 0xffff0000u, h1 = b1 & 0xffff0000u;
    hi = (b0 >> 16) | h1;
    float l0 = a0 - u2f(h0), l1 = a1 - u2f(h1);
    lo = (f2u(l0) >> 16) | (f2u(l1) & 0xffff0000u);
}

__device__ __forceinline__ float sigm(float x){ return 1.f / (1.f + __expf(-x)); }
__device__ __forceinline__ float tanh_f(float x){ return 1.f - 2.f / (1.f + __expf(2.f * x)); }

__device__ __forceinline__ void gload16(const u16* g, u16* l){
    __builtin_amdgcn_global_load_lds(
        (const __attribute__((address_space(1))) u32*)g,
        (__attribute__((address_space(3))) u32*)l, 16, 0, 0);
}

// ---------------- weight split prep ----------------
__global__ __launch_bounds__(256) void split_kernel(
    const float* __restrict__ src, int npairs, u16* __restrict__ hi, u16* __restrict__ lo)
{
    int i = blockIdx.x * 256 + threadIdx.x;
    if (i < npairs){
        float2 a = ((const float2*)src)[i];
        u32 h, l; split2(a.x, a.y, h, l);
        ((u32*)hi)[i] = h; ((u32*)lo)[i] = l;
    }
}

// ---------------- Wc = wih_g @ We, ebg = wih_g @ eb  (block = (l,g)) -------
__global__ __launch_bounds__(256) void wcombine_kernel(
    const float* __restrict__ WIH, const float* __restrict__ EW,
    const float* __restrict__ EB,
    u16* __restrict__ wc_hi, u16* __restrict__ wc_lo, float* __restrict__ ebg)
{
    __shared__ float WeL[16384];
    const int l = blockIdx.x / 3, g = blockIdx.x % 3;
    const int t = threadIdx.x;
    for (int u = t; u < 4096; u += 256)
        ((float4*)WeL)[u] = ((const float4*)(EW + (size_t)l * 16384))[u];
    __syncthreads();

    const int r = t >> 1, jh = (t & 1) * 64;
    const float* wr = WIH + ((size_t)l * 384 + g * 128 + r) * 128;
    float a[64];
#pragma unroll
    for (int j = 0; j < 64; ++j) a[j] = 0.f;
    for (int k = 0; k < 128; ++k){
        const float wv = wr[k];
        const float4* wel = (const float4*)(WeL + k * 128 + jh);
#pragma unroll
        for (int jj = 0; jj < 16; ++jj){
            float4 v = wel[jj];
            a[jj*4+0] = fmaf(wv, v.x, a[jj*4+0]);
            a[jj*4+1] = fmaf(wv, v.y, a[jj*4+1]);
            a[jj*4+2] = fmaf(wv, v.z, a[jj*4+2]);
            a[jj*4+3] = fmaf(wv, v.w, a[jj*4+3]);
        }
    }
    const size_t base = ((size_t)(l * 3 + g) * 16384 + r * 128 + jh);
#pragma unroll
    for (int j = 0; j < 64; j += 2){
        u32 hb, lb; split2(a[j], a[j+1], hb, lb);
        ((u32*)wc_hi)[(base + j) >> 1] = hb;
        ((u32*)wc_lo)[(base + j) >> 1] = lb;
    }
    if (t < 128){
        const float* wr2 = WIH + ((size_t)l * 384 + g * 128 + t) * 128;
        const float* eb = EB + (size_t)l * 128;
        float s = 0.f;
        for (int k = 0; k < 128; ++k) s = fmaf(wr2[k], eb[k], s);
        ebg[(l * 3 + g) * 128 + t] = s;
    }
}

// ---------------- proj: h = relu(NF @ Wp.T + bp), pair out -----------------
__global__ __launch_bounds__(256) void proj_kernel(
    const float* __restrict__ A,
    const u16* __restrict__ Whi, const u16* __restrict__ Wlo,   // [128][256] split
    const float* __restrict__ bias,
    u16* __restrict__ Ohi, u16* __restrict__ Olo, int M)
{
    constexpr int K = 256;
    __shared__ __align__(16) u16 ldsB[8192];   // [hl][kg4][row128][8] = 16KB
    const int tid = threadIdx.x, lane = tid & 63, w = tid >> 6;
    const int m0 = blockIdx.x * 128;

    f32x4 acc[2][8];
#pragma unroll
    for (int a = 0; a < 2; ++a)
#pragma unroll
        for (int b = 0; b < 8; ++b) acc[a][b] = (f32x4){0.f, 0.f, 0.f, 0.f};

    for (int ks = 0; ks < K / 32; ++ks){
        // linear-lane staging: thread u writes u16 flat u*8 (conflict-free)
        for (int u = tid; u < 1024; u += 256){
            int flat = u * 8;
            int hl = flat >> 12, rem = flat & 4095;
            int kg = rem >> 10, row = (rem >> 3) & 127;
            const u16* srcp = hl ? Wlo : Whi;
            bf16x8 v = *(const bf16x8*)&srcp[row * K + ks * 32 + kg * 8];
            *(bf16x8*)&ldsB[flat] = v;
        }
        __syncthreads();

        bf16x8 ah[2], al[2];
#pragma unroll
        for (int mf = 0; mf < 2; ++mf){
            int row = m0 + w * 32 + mf * 16 + (lane & 15);
            row = row < M ? row : M - 1;
            const float* ap = A + (size_t)row * K + ks * 32 + (lane >> 4) * 8;
            float4 fa = *(const float4*)ap;
            float4 fb = *(const float4*)(ap + 4);
            union{ bf16x8 v; u32 u[4]; } H, L;
            split2(fa.x, fa.y, H.u[0], L.u[0]);
            split2(fa.z, fa.w, H.u[1], L.u[1]);
            split2(fb.x, fb.y, H.u[2], L.u[2]);
            split2(fb.z, fb.w, H.u[3], L.u[3]);
            ah[mf] = H.v; al[mf] = L.v;
        }
#pragma unroll
        for (int nf = 0; nf < 8; ++nf){
            int bi = (lane >> 4) * 1024 + (nf * 16 + (lane & 15)) * 8;
            bf16x8 bh = *(const bf16x8*)&ldsB[bi];
            bf16x8 bl = *(const bf16x8*)&ldsB[bi + 4096];
#pragma unroll
            for (int mf = 0; mf < 2; ++mf){
                acc[mf][nf] = __builtin_amdgcn_mfma_f32_16x16x32_bf16(ah[mf], bh, acc[mf][nf], 0, 0, 0);
                acc[mf][nf] = __builtin_amdgcn_mfma_f32_16x16x32_bf16(ah[mf], bl, acc[mf][nf], 0, 0, 0);
                acc[mf][nf] = __builtin_amdgcn_mfma_f32_16x16x32_bf16(al[mf], bh, acc[mf][nf], 0, 0, 0);
            }
        }
        __syncthreads();
    }
#pragma unroll
    for (int mf = 0; mf < 2; ++mf)
#pragma unroll
        for (int nf = 0; nf < 8; ++nf){
            int col = nf * 16 + (lane & 15);
#pragma unroll
            for (int r = 0; r < 4; ++r){
                int grow = m0 + w * 32 + mf * 16 + (lane >> 4) * 4 + r;
                if (grow < M){
                    float v = acc[mf][nf][r] + bias[col];
                    v = fmaxf(v, 0.f);
                    u32 b = f2u(v);
                    float lv = v - u2f(b & 0xffff0000u);
                    size_t o = (size_t)grow * HID + col;
                    Ohi[o] = (u16)(b >> 16);
                    Olo[o] = (u16)(f2u(lv) >> 16);
                }
            }
        }
}

// ---------------- fused GRU: wave-per-plane, mt=4, gload_lds staging -------
// Block 256 thr = 4 waves, BM=64 rows.
// wave0: R (K=256 concat [s|h] vs [WcR;whhR]); wave1: Z; wave2: I (s, ks<4);
// wave3: H (h, ks>=4). acc[4][8] per wave = its plane, 64 rows x 128 cols.
// LDS per ks (u16): A[hl][kg4][row64][8] @0 (4096) ; B p=0..2
// [hl][kg4][col128][8] @4096+p*8192. Total 28672 u16 = 56KB.
template<int LAST>
__global__ __launch_bounds__(256, 2) void gru_fused(
    const u16* __restrict__ s_hi,  const u16* __restrict__ s_lo,
    const u16* __restrict__ h_hi,  const u16* __restrict__ h_lo,
    const u16* __restrict__ wc_hi, const u16* __restrict__ wc_lo,    // [3][128][128]
    const u16* __restrict__ whh_hi,const u16* __restrict__ whh_lo,   // [3][128][128]
    const float* __restrict__ ebg,                                   // [3][128]
    const float* __restrict__ bih, const float* __restrict__ bhh,    // [384]
    const float* __restrict__ degf,
    u16* __restrict__ out_hi, u16* __restrict__ out_lo, float* __restrict__ outf,
    int M)
{
    __shared__ __align__(16) u16 lds[28672];     // 56KB
    const int tid = threadIdx.x, lane = tid & 63, w = tid >> 6;
    const int m0 = blockIdx.x * 64;

    f32x4 acc[4][8];
#pragma unroll
    for (int a = 0; a < 4; ++a)
#pragma unroll
        for (int b = 0; b < 8; ++b) acc[a][b] = (f32x4){0.f,0.f,0.f,0.f};

    const int p = (w < 2) ? w : 2;      // B slab index for this wave

    for (int ks = 0; ks < 8; ++ks){
        const bool sside = ks < 4;
        const int kk = (ks & 3) * 32;
        const u16* Ah = sside ? s_hi : h_hi;
        const u16* Al = sside ? s_lo : h_lo;
        const u16* Bh = sside ? wc_hi : whh_hi;
        const u16* Bl = sside ? wc_lo : whh_lo;

        // stage 56 x 1KB chunks via global_load_lds (wave-linear dest)
        for (int c = w; c < 56; c += 4){
            const int flat = c * 512 + lane * 8;
            const u16* gsrc;
            if (flat < 4096){
                int hl = flat >> 11, rem = flat & 2047;
                int kg = rem >> 9, row = (rem >> 3) & 63;
                int gr = m0 + row; gr = gr < M ? gr : M - 1;
                gsrc = (hl ? Al : Ah) + (size_t)gr * HID + kk + kg * 8;
            } else {
                int f2 = flat - 4096;
                int ps = f2 >> 13, rem = f2 & 8191;
                int hl = rem >> 12, kg = (rem >> 10) & 3, col = (rem >> 3) & 127;
                gsrc = (hl ? Bl : Bh) + ps * 16384 + col * 128 + kk + kg * 8;
            }
            gload16(gsrc, &lds[flat]);
        }
        __syncthreads();

        const bool active = (w < 2) || ((w == 2) == sside);
        if (active){
            bf16x8 ah[4], al[4];
#pragma unroll
            for (int mf = 0; mf < 4; ++mf){
                const int ai = (lane >> 4) * 512 + (mf * 16 + (lane & 15)) * 8;
                ah[mf] = *(const bf16x8*)&lds[ai];
                al[mf] = *(const bf16x8*)&lds[ai + 2048];
            }
            const int bB = 4096 + p * 8192 + (lane >> 4) * 1024 + (lane & 15) * 8;
#pragma unroll
            for (int nf = 0; nf < 8; ++nf){
                bf16x8 bh = *(const bf16x8*)&lds[bB + nf * 128];
                bf16x8 bl = *(const bf16x8*)&lds[bB + nf * 128 + 4096];
#pragma unroll
                for (int mf = 0; mf < 4; ++mf){
                    acc[mf][nf] = __builtin_amdgcn_mfma_f32_16x16x32_bf16(ah[mf], bh, acc[mf][nf], 0, 0, 0);
                    acc[mf][nf] = __builtin_amdgcn_mfma_f32_16x16x32_bf16(ah[mf], bl, acc[mf][nf], 0, 0, 0);
                    acc[mf][nf] = __builtin_amdgcn_mfma_f32_16x16x32_bf16(al[mf], bh, acc[mf][nf], 0, 0, 0);
                }
            }
        }
        __syncthreads();
    }

    // epilogue: exchange planes via padded LDS, 16-row quarters
    float* planes = (float*)lds;         // [4 planes][16][132] f32 = 33KB
#pragma unroll 4
    for (int q = 0; q < 4; ++q){
#pragma unroll
        for (int nf = 0; nf < 8; ++nf){
#pragma unroll
            for (int r = 0; r < 4; ++r){
                const int row16 = (lane >> 4) * 4 + r;
                const int col = nf * 16 + (lane & 15);
                planes[w * 2112 + row16 * 132 + col] = acc[q][nf][r];
            }
        }
        __syncthreads();
        {
            const int row16 = tid >> 4;
            const int c0 = (tid & 15) * 8;
            const int gr = m0 + q * 16 + row16;
            if (gr < M){
                const float dgv = degf[gr];
                const size_t base = (size_t)gr * HID + c0;
                const int sw = row16 * 132 + c0;
                union{ bf16x8 v; u16 e[8]; } Hh, Hl;
                Hh.v = *(const bf16x8*)&h_hi[base];
                Hl.v = *(const bf16x8*)&h_lo[base];
                float o[8];
#pragma unroll
                for (int j = 0; j < 8; ++j){
                    const int c = c0 + j;
                    const float R  = planes[sw + j];
                    const float Z  = planes[2112 + sw + j];
                    const float NI = planes[4224 + sw + j];
                    const float NH = planes[6336 + sw + j];
                    const float rg = sigm(R + dgv * ebg[c] + bih[c] + bhh[c]);
                    const float zg = sigm(Z + dgv * ebg[128 + c] + bih[128 + c] + bhh[128 + c]);
                    const float hv = u2f((u32)Hh.e[j] << 16) + u2f((u32)Hl.e[j] << 16);
                    const float nn = tanh_f(NI + dgv * ebg[256 + c] + bih[256 + c]
                                            + rg * (NH + bhh[256 + c]));
                    o[j] = nn + zg * (hv - nn);
                }
                if (LAST){
                    *(float4*)&outf[base]     = make_float4(o[0], o[1], o[2], o[3]);
                    *(float4*)&outf[base + 4] = make_float4(o[4], o[5], o[6], o[7]);
                } else {
#pragma unroll
                    for (int j = 0; j < 4; ++j){
                        u32 hb, lb; split2(o[2*j], o[2*j+1], hb, lb);
                        ((u32*)out_hi)[(base >> 1) + j] = hb;
                        ((u32*)out_lo)[(base >> 1) + j] = lb;
                    }
                }
            }
        }
        __syncthreads();
    }
}

// ---------------- CSR build (int atomics only) ----------------
__global__ __launch_bounds__(256) void hist_kernel(
    const int* __restrict__ dst, int* __restrict__ degi, int E)
{
    const int t = blockIdx.x * 256 + threadIdx.x;
    if (t < E) atomicAdd(&degi[dst[t]], 1);
}

__global__ __launch_bounds__(256) void reduce_kernel(
    const int* __restrict__ degi, int* __restrict__ bsum, int N)
{
    const int base = blockIdx.x * 1024;
    const int t = threadIdx.x;
    int s = 0;
#pragma unroll
    for (int k = 0; k < 4; ++k){
        const int i = base + t * 4 + k;
        if (i < N) s += degi[i];
    }
    __shared__ int sh[256];
    sh[t] = s; __syncthreads();
    for (int off = 128; off > 0; off >>= 1){
        if (t < off) sh[t] += sh[t + off];
        __syncthreads();
    }
    if (t == 0) bsum[blockIdx.x] = sh[0];
}

__global__ __launch_bounds__(256) void scanb_kernel(
    const int* __restrict__ bsum, int* __restrict__ boff, int NB,
    int* __restrict__ rowptr, int N, int E)
{
    const int t = threadIdx.x;
    const int v = (t < NB) ? bsum[t] : 0;
    __shared__ int sh[256];
    sh[t] = v; __syncthreads();
    for (int off = 1; off < 256; off <<= 1){
        const int x = (t >= off) ? sh[t - off] : 0;
        __syncthreads();
        sh[t] += x;
        __syncthreads();
    }
    if (t < NB) boff[t] = sh[t] - v;
    if (t == 0) rowptr[N] = E;
}

__global__ __launch_bounds__(256) void scan_kernel(
    const int* __restrict__ degi, const int* __restrict__ boff,
    int* __restrict__ rowptr, int* __restrict__ cursor,
    float* __restrict__ degf, int N)
{
    const int base = blockIdx.x * 1024;
    const int t = threadIdx.x;
    int v[4]; int s = 0;
    const int i0 = base + t * 4;
#pragma unroll
    for (int k = 0; k < 4; ++k){
        const int i = i0 + k;
        v[k] = (i < N) ? degi[i] : 0;
        s += v[k];
    }
    __shared__ int sh[256];
    sh[t] = s; __syncthreads();
    for (int off = 1; off < 256; off <<= 1){
        const int x = (t >= off) ? sh[t - off] : 0;
        __syncthreads();
        sh[t] += x;
        __syncthreads();
    }
    int excl = sh[t] - s + boff[blockIdx.x];
#pragma unroll
    for (int k = 0; k < 4; ++k){
        const int i = i0 + k;
        if (i < N){
            rowptr[i] = excl;
            cursor[i] = excl;
            degf[i]   = (float)v[k];
            excl += v[k];
        }
    }
}

__global__ __launch_bounds__(256) void fill_kernel(
    const int* __restrict__ src, const int* __restrict__ dst,
    int* __restrict__ cursor, int* __restrict__ col, int E)
{
    const int e = blockIdx.x * 256 + threadIdx.x;
    if (e < E){
        const int p = atomicAdd(&cursor[dst[e]], 1);
        col[p] = src[e];
    }
}

// ---------------- gather aggregation (pair in / pair out) ----------------
__global__ __launch_bounds__(256) void gather_kernel(
    const u32* __restrict__ hhi, const u32* __restrict__ hlo,
    const int* __restrict__ rowptr, const int* __restrict__ col,
    u32* __restrict__ shi, u32* __restrict__ slo, int N)
{
    const int node = blockIdx.x * 4 + (threadIdx.x >> 6);
    const int lane = threadIdx.x & 63;
    if (node >= N) return;
    const int beg = rowptr[node], end = rowptr[node + 1];
    float a0 = 0.f, a1 = 0.f, b0 = 0.f, b1 = 0.f;
    int j = beg;
    for (; j + 1 < end; j += 2){
        int c0 = col[j], c1 = col[j + 1];
        u32 vh0 = hhi[(size_t)c0 * 64 + lane], vl0 = hlo[(size_t)c0 * 64 + lane];
        u32 vh1 = hhi[(size_t)c1 * 64 + lane], vl1 = hlo[(size_t)c1 * 64 + lane];
        a0 += u2f(vh0 << 16) + u2f(vl0 << 16);
        a1 += u2f(vh0 & 0xffff0000u) + u2f(vl0 & 0xffff0000u);
        b0 += u2f(vh1 << 16) + u2f(vl1 << 16);
        b1 += u2f(vh1 & 0xffff0000u) + u2f(vl1 & 0xffff0000u);
    }
    if (j < end){
        int c0 = col[j];
        u32 vh = hhi[(size_t)c0 * 64 + lane], vl = hlo[(size_t)c0 * 64 + lane];
        a0 += u2f(vh << 16) + u2f(vl << 16);
        a1 += u2f(vh & 0xffff0000u) + u2f(vl & 0xffff0000u);
    }
    a0 += b0; a1 += b1;
    u32 ho, lo; split2(a0, a1, ho, lo);
    shi[(size_t)node * 64 + lane] = ho;
    slo[(size_t)node * 64 + lane] = lo;
}

extern "C" void kernel_launch(void* const* d_in, const int* in_sizes, int n_in,
                              void* d_out, int out_size, void* d_ws, size_t ws_size,
                              hipStream_t stream)
{
    const float* NF  = (const float*)d_in[0];   // [N,256]
    const int*   EI  = (const int*)  d_in[1];   // [2,E]
    const float* Wp  = (const float*)d_in[3];   // [128,256]
    const float* bp  = (const float*)d_in[4];   // [128]
    const float* EW  = (const float*)d_in[5];   // [2,1,128,128]
    const float* EB  = (const float*)d_in[6];   // [2,1,128]
    const float* WIH = (const float*)d_in[7];   // [2,384,128]
    const float* WHH = (const float*)d_in[8];   // [2,384,128]
    const float* BIH = (const float*)d_in[9];   // [2,384]
    const float* BHH = (const float*)d_in[10];  // [2,384]
    float* out = (float*)d_out;

    const int FEAT = 256;
    const int N = in_sizes[0] / FEAT;           // 100000
    const int E = in_sizes[1] / 2;              // 640000
    const size_t NH = (size_t)N * HID;
    const int NB = (N + 1023) / 1024;

    u16* h_hi = (u16*)d_ws;
    u16* h_lo = h_hi + NH;
    u16* s_hi = h_lo + NH;
    u16* s_lo = s_hi + NH;
    float* degf = (float*)(s_lo + NH);
    u16* wp_hi  = (u16*)(degf + N);
    u16* wp_lo  = wp_hi + 32768;
    u16* whh_hi = wp_lo + 32768;    // 2 layers x 49152
    u16* whh_lo = whh_hi + 98304;
    u16* wc_hi  = whh_lo + 98304;   // 2 layers x 3 x 16384
    u16* wc_lo  = wc_hi + 98304;
    float* ebg  = (float*)(wc_lo + 98304);   // 2 x 384
    int* degi   = (int*)(ebg + 768);
    int* rowptr = degi + N;
    int* cursor = rowptr + N + 1;
    int* colA   = cursor + N;
    int* bsum   = colA + E;
    int* boff   = bsum + 256;

    // weight prep
    split_kernel<<<64, 256, 0, stream>>>(Wp, 16384, wp_hi, wp_lo);
    split_kernel<<<192, 256, 0, stream>>>(WHH, 49152, whh_hi, whh_lo);
    wcombine_kernel<<<6, 256, 0, stream>>>(WIH, EW, EB, wc_hi, wc_lo, ebg);

    // h = relu(NF @ Wp.T + bp)
    proj_kernel<<<(N + 127) / 128, 256, 0, stream>>>(NF, wp_hi, wp_lo, bp, h_hi, h_lo, N);

    // CSR of dst (shared by both layers)
    hipMemsetAsync(degi, 0, N * sizeof(int), stream);
    hist_kernel<<<(E + 255) / 256, 256, 0, stream>>>(EI + E, degi, E);
    reduce_kernel<<<NB, 256, 0, stream>>>(degi, bsum, N);
    scanb_kernel<<<1, 256, 0, stream>>>(bsum, boff, NB, rowptr, N, E);
    scan_kernel<<<NB, 256, 0, stream>>>(degi, boff, rowptr, cursor, degf, N);
    fill_kernel<<<(E + 255) / 256, 256, 0, stream>>>(EI, EI + E, cursor, colA, E);

    for (int l = 0; l < 2; ++l){
        gather_kernel<<<(N + 3) / 4, 256, 0, stream>>>(
            (const u32*)h_hi, (const u32*)h_lo, rowptr, colA,
            (u32*)s_hi, (u32*)s_lo, N);
        if (l == 0)
            gru_fused<0><<<(N + 63) / 64, 256, 0, stream>>>(
                s_hi, s_lo, h_hi, h_lo,
                wc_hi + l * 49152, wc_lo + l * 49152,
                whh_hi + l * 49152, whh_lo + l * 49152,
                ebg + l * 384, BIH + l * 384, BHH + l * 384, degf,
                h_hi, h_lo, nullptr, N);
        else
            gru_fused<1><<<(N + 63) / 64, 256, 0, stream>>>(
                s_hi, s_lo, h_hi, h_lo,
                wc_hi + l * 49152, wc_lo + l * 49152,
                whh_hi + l * 49152, whh_lo + l * 49152,
                ebg + l * 384, BIH + l * 384, BHH + l * 384, degf,
                nullptr, nullptr, out, N);
    }
}

// Round 6
// 733.151 us; speedup vs baseline: 4.7561x; 1.0168x over previous
//
#include <hip/hip_runtime.h>
#include <hip/hip_bf16.h>

// ---------------------------------------------------------------------------
// BasicGNNEncoder, MFMA bf16x3 (split hi/lo), agg-GEMM folded into GRU.
//   h = relu(NF @ Wp.T + bp)
//   Wc_g = wih_g @ We ; ebg_g = wih_g @ eb      (per layer, on device)
//   2x { s = segsum(h[src], dst) [CSR gather];
//        gates = s@Wc.T + deg*ebg + h@whh.T + biases ; h = GRU blend }
// gru_fused v3: barrier-free K-loop. A-tile (s|h, hi|lo, 64KB) staged ONCE
// via global_load_lds; B fragments loaded straight from global (L2-hot
// weights) into VGPRs; wave-per-plane (R,Z K=256; I on s; H on h), mt=4.
// ---------------------------------------------------------------------------

typedef unsigned int u32;
typedef unsigned short u16;
typedef __attribute__((ext_vector_type(8))) short bf16x8;   // 8 bf16 = 4 VGPR
typedef __attribute__((ext_vector_type(4))) float f32x4;

#define HID 128

__device__ __forceinline__ float u2f(u32 b){ union{u32 u; float f;} v; v.u=b; return v.f; }
__device__ __forceinline__ u32 f2u(float f){ union{u32 u; float f;} v; v.f=f; return v.u; }

__device__ __forceinline__ void split2(float a0, float a1, u32& hi, u32& lo){
    u32 b0 = f2u(a0), b1 = f2u(a1);
    u32 h0 = b0 & 0xffff0000u, h1 = b1 & 0xffff0000u;
    hi = (b0 >> 16) | h1;
    float l0 = a0 - u2f(h0), l1 = a1 - u2f(h1);
    lo = (f2u(l0) >> 16) | (f2u(l1) & 0xffff0000u);
}

__device__ __forceinline__ float sigm(float x){ return 1.f / (1.f + __expf(-x)); }
__device__ __forceinline__ float tanh_f(float x){ return 1.f - 2.f / (1.f + __expf(2.f * x)); }

__device__ __forceinline__ void gload16(const u16* g, u16* l){
    __builtin_amdgcn_global_load_lds(
        (const __attribute__((address_space(1))) u32*)g,
        (__attribute__((address_space(3))) u32*)l, 16, 0, 0);
}

// ---------------- weight split prep ----------------
__global__ __launch_bounds__(256) void split_kernel(
    const float* __restrict__ src, int npairs, u16* __restrict__ hi, u16* __restrict__ lo)
{
    int i = blockIdx.x * 256 + threadIdx.x;
    if (i < npairs){
        float2 a = ((const float2*)src)[i];
        u32 h, l; split2(a.x, a.y, h, l);
        ((u32*)hi)[i] = h; ((u32*)lo)[i] = l;
    }
}

// ---------------- Wc = wih_g @ We, ebg = wih_g @ eb  (block = (l,g)) -------
__global__ __launch_bounds__(256) void wcombine_kernel(
    const float* __restrict__ WIH, const float* __restrict__ EW,
    const float* __restrict__ EB,
    u16* __restrict__ wc_hi, u16* __restrict__ wc_lo, float* __restrict__ ebg)
{
    __shared__ float WeL[16384];
    const int l = blockIdx.x / 3, g = blockIdx.x % 3;
    const int t = threadIdx.x;
    for (int u = t; u < 4096; u += 256)
        ((float4*)WeL)[u] = ((const float4*)(EW + (size_t)l * 16384))[u];
    __syncthreads();

    const int r = t >> 1, jh = (t & 1) * 64;
    const float* wr = WIH + ((size_t)l * 384 + g * 128 + r) * 128;
    float a[64];
#pragma unroll
    for (int j = 0; j < 64; ++j) a[j] = 0.f;
    for (int k = 0; k < 128; ++k){
        const float wv = wr[k];
        const float4* wel = (const float4*)(WeL + k * 128 + jh);
#pragma unroll
        for (int jj = 0; jj < 16; ++jj){
            float4 v = wel[jj];
            a[jj*4+0] = fmaf(wv, v.x, a[jj*4+0]);
            a[jj*4+1] = fmaf(wv, v.y, a[jj*4+1]);
            a[jj*4+2] = fmaf(wv, v.z, a[jj*4+2]);
            a[jj*4+3] = fmaf(wv, v.w, a[jj*4+3]);
        }
    }
    const size_t base = ((size_t)(l * 3 + g) * 16384 + r * 128 + jh);
#pragma unroll
    for (int j = 0; j < 64; j += 2){
        u32 hb, lb; split2(a[j], a[j+1], hb, lb);
        ((u32*)wc_hi)[(base + j) >> 1] = hb;
        ((u32*)wc_lo)[(base + j) >> 1] = lb;
    }
    if (t < 128){
        const float* wr2 = WIH + ((size_t)l * 384 + g * 128 + t) * 128;
        const float* eb = EB + (size_t)l * 128;
        float s = 0.f;
        for (int k = 0; k < 128; ++k) s = fmaf(wr2[k], eb[k], s);
        ebg[(l * 3 + g) * 128 + t] = s;
    }
}

// ---------------- proj: h = relu(NF @ Wp.T + bp), pair out -----------------
__global__ __launch_bounds__(256) void proj_kernel(
    const float* __restrict__ A,
    const u16* __restrict__ Whi, const u16* __restrict__ Wlo,   // [128][256] split
    const float* __restrict__ bias,
    u16* __restrict__ Ohi, u16* __restrict__ Olo, int M)
{
    constexpr int K = 256;
    __shared__ __align__(16) u16 ldsB[8192];   // [hl][kg4][row128][8] = 16KB
    const int tid = threadIdx.x, lane = tid & 63, w = tid >> 6;
    const int m0 = blockIdx.x * 128;

    f32x4 acc[2][8];
#pragma unroll
    for (int a = 0; a < 2; ++a)
#pragma unroll
        for (int b = 0; b < 8; ++b) acc[a][b] = (f32x4){0.f, 0.f, 0.f, 0.f};

    for (int ks = 0; ks < K / 32; ++ks){
        for (int u = tid; u < 1024; u += 256){
            int flat = u * 8;
            int hl = flat >> 12, rem = flat & 4095;
            int kg = rem >> 10, row = (rem >> 3) & 127;
            const u16* srcp = hl ? Wlo : Whi;
            bf16x8 v = *(const bf16x8*)&srcp[row * K + ks * 32 + kg * 8];
            *(bf16x8*)&ldsB[flat] = v;
        }
        __syncthreads();

        bf16x8 ah[2], al[2];
#pragma unroll
        for (int mf = 0; mf < 2; ++mf){
            int row = m0 + w * 32 + mf * 16 + (lane & 15);
            row = row < M ? row : M - 1;
            const float* ap = A + (size_t)row * K + ks * 32 + (lane >> 4) * 8;
            float4 fa = *(const float4*)ap;
            float4 fb = *(const float4*)(ap + 4);
            union{ bf16x8 v; u32 u[4]; } H, L;
            split2(fa.x, fa.y, H.u[0], L.u[0]);
            split2(fa.z, fa.w, H.u[1], L.u[1]);
            split2(fb.x, fb.y, H.u[2], L.u[2]);
            split2(fb.z, fb.w, H.u[3], L.u[3]);
            ah[mf] = H.v; al[mf] = L.v;
        }
#pragma unroll
        for (int nf = 0; nf < 8; ++nf){
            int bi = (lane >> 4) * 1024 + (nf * 16 + (lane & 15)) * 8;
            bf16x8 bh = *(const bf16x8*)&ldsB[bi];
            bf16x8 bl = *(const bf16x8*)&ldsB[bi + 4096];
#pragma unroll
            for (int mf = 0; mf < 2; ++mf){
                acc[mf][nf] = __builtin_amdgcn_mfma_f32_16x16x32_bf16(ah[mf], bh, acc[mf][nf], 0, 0, 0);
                acc[mf][nf] = __builtin_amdgcn_mfma_f32_16x16x32_bf16(ah[mf], bl, acc[mf][nf], 0, 0, 0);
                acc[mf][nf] = __builtin_amdgcn_mfma_f32_16x16x32_bf16(al[mf], bh, acc[mf][nf], 0, 0, 0);
            }
        }
        __syncthreads();
    }
#pragma unroll
    for (int mf = 0; mf < 2; ++mf)
#pragma unroll
        for (int nf = 0; nf < 8; ++nf){
            int col = nf * 16 + (lane & 15);
#pragma unroll
            for (int r = 0; r < 4; ++r){
                int grow = m0 + w * 32 + mf * 16 + (lane >> 4) * 4 + r;
                if (grow < M){
                    float v = acc[mf][nf][r] + bias[col];
                    v = fmaxf(v, 0.f);
                    u32 b = f2u(v);
                    float lv = v - u2f(b & 0xffff0000u);
                    size_t o = (size_t)grow * HID + col;
                    Ohi[o] = (u16)(b >> 16);
                    Olo[o] = (u16)(f2u(lv) >> 16);
                }
            }
        }
}

// ---------------- fused GRU v3: barrier-free K-loop ------------------------
// Block 256 thr = 4 waves, BM=64 rows. plane = (w + blockIdx) & 3:
//   plane0: R (K=256, s then h, slab0) ; plane1: Z (slab1)
//   plane2: I (K=128 on s, wc slab2)   ; plane3: H (K=128 on h, whh slab2)
// A tile (2 side x 2 hl x 16 kg x 64 row x 8) = 64KB staged once by
// global_load_lds; B frags loaded per-ks straight from global (L2-hot).
// Epilogue: plane exchange via padded LDS (reuses A buffer).
template<int LAST>
__global__ __launch_bounds__(256, 2) void gru_fused(
    const u16* __restrict__ s_hi,  const u16* __restrict__ s_lo,
    const u16* __restrict__ h_hi,  const u16* __restrict__ h_lo,
    const u16* __restrict__ wc_hi, const u16* __restrict__ wc_lo,    // [3][128][128]
    const u16* __restrict__ whh_hi,const u16* __restrict__ whh_lo,   // [3][128][128]
    const float* __restrict__ ebg,                                   // [3][128]
    const float* __restrict__ bih, const float* __restrict__ bhh,    // [384]
    const float* __restrict__ degf,
    u16* __restrict__ out_hi, u16* __restrict__ out_lo, float* __restrict__ outf,
    int M)
{
    __shared__ __align__(16) u16 lds[32768];     // 64KB A-tile / epilogue planes
    const int tid = threadIdx.x, lane = tid & 63, w = tid >> 6;
    const int m0 = blockIdx.x * 64;
    const int plane = (w + blockIdx.x) & 3;
    const int slab = (plane < 2) ? plane : 2;

    // ---- stage A tile once: 64 chunks x 1KB (lane = row) ----
    {
        int gr = m0 + lane; gr = gr < M ? gr : M - 1;
        const size_t ro = (size_t)gr * HID;
#pragma unroll
        for (int i = 0; i < 16; ++i){
            const int c = w * 16 + i;
            const int side = c >> 5, hl = (c >> 4) & 1, kg = c & 15;
            const u16* base = side ? (hl ? h_lo : h_hi) : (hl ? s_lo : s_hi);
            gload16(base + ro + kg * 8, &lds[c * 512 + lane * 8]);
        }
    }
    __syncthreads();

    f32x4 acc[4][8];
#pragma unroll
    for (int a = 0; a < 4; ++a)
#pragma unroll
        for (int b = 0; b < 8; ++b) acc[a][b] = (f32x4){0.f,0.f,0.f,0.f};

    // ---- barrier-free K loop ----
    for (int ks = 0; ks < 8; ++ks){
        const bool sside = ks < 4;
        const bool active = (plane < 2) || ((plane == 2) == sside);
        if (!active) continue;

        const u16* Bh = (sside ? wc_hi : whh_hi) + slab * 16384;
        const u16* Bl = (sside ? wc_lo : whh_lo) + slab * 16384;

        // A frags from LDS (conflict-free: 16B stride across lanes)
        const int abase = (sside ? 0 : 16384) + ((ks & 3) * 4 + (lane >> 4)) * 512
                        + (lane & 15) * 8;
        bf16x8 ah[4], al[4];
#pragma unroll
        for (int mf = 0; mf < 4; ++mf){
            ah[mf] = *(const bf16x8*)&lds[abase + mf * 128];
            al[mf] = *(const bf16x8*)&lds[abase + mf * 128 + 8192];
        }

        const int boff = (lane & 15) * 128 + (ks & 3) * 32 + (lane >> 4) * 8;
#pragma unroll
        for (int nf = 0; nf < 8; ++nf){
            bf16x8 bh = *(const bf16x8*)&Bh[nf * 2048 + boff];
            bf16x8 bl = *(const bf16x8*)&Bl[nf * 2048 + boff];
#pragma unroll
            for (int mf = 0; mf < 4; ++mf){
                acc[mf][nf] = __builtin_amdgcn_mfma_f32_16x16x32_bf16(ah[mf], bh, acc[mf][nf], 0, 0, 0);
                acc[mf][nf] = __builtin_amdgcn_mfma_f32_16x16x32_bf16(ah[mf], bl, acc[mf][nf], 0, 0, 0);
                acc[mf][nf] = __builtin_amdgcn_mfma_f32_16x16x32_bf16(al[mf], bh, acc[mf][nf], 0, 0, 0);
            }
        }
    }

    __syncthreads();    // A-tile reads done; lds becomes plane-exchange buffer

    // ---- epilogue: exchange planes via padded LDS, 16-row quarters ----
    float* planes = (float*)lds;         // [4 planes][16][132] f32 = 33.8KB
#pragma unroll 4
    for (int q = 0; q < 4; ++q){
#pragma unroll
        for (int nf = 0; nf < 8; ++nf){
#pragma unroll
            for (int r = 0; r < 4; ++r){
                const int row16 = (lane >> 4) * 4 + r;
                const int col = nf * 16 + (lane & 15);
                planes[plane * 2112 + row16 * 132 + col] = acc[q][nf][r];
            }
        }
        __syncthreads();
        {
            const int row16 = tid >> 4;
            const int c0 = (tid & 15) * 8;
            const int gr = m0 + q * 16 + row16;
            if (gr < M){
                const float dgv = degf[gr];
                const size_t base = (size_t)gr * HID + c0;
                const int sw = row16 * 132 + c0;
                union{ bf16x8 v; u16 e[8]; } Hh, Hl;
                Hh.v = *(const bf16x8*)&h_hi[base];
                Hl.v = *(const bf16x8*)&h_lo[base];
                float o[8];
#pragma unroll
                for (int j = 0; j < 8; ++j){
                    const int c = c0 + j;
                    const float R  = planes[sw + j];
                    const float Z  = planes[2112 + sw + j];
                    const float NI = planes[4224 + sw + j];
                    const float NH = planes[6336 + sw + j];
                    const float rg = sigm(R + dgv * ebg[c] + bih[c] + bhh[c]);
                    const float zg = sigm(Z + dgv * ebg[128 + c] + bih[128 + c] + bhh[128 + c]);
                    const float hv = u2f((u32)Hh.e[j] << 16) + u2f((u32)Hl.e[j] << 16);
                    const float nn = tanh_f(NI + dgv * ebg[256 + c] + bih[256 + c]
                                            + rg * (NH + bhh[256 + c]));
                    o[j] = nn + zg * (hv - nn);
                }
                if (LAST){
                    *(float4*)&outf[base]     = make_float4(o[0], o[1], o[2], o[3]);
                    *(float4*)&outf[base + 4] = make_float4(o[4], o[5], o[6], o[7]);
                } else {
#pragma unroll
                    for (int j = 0; j < 4; ++j){
                        u32 hb, lb; split2(o[2*j], o[2*j+1], hb, lb);
                        ((u32*)out_hi)[(base >> 1) + j] = hb;
                        ((u32*)out_lo)[(base >> 1) + j] = lb;
                    }
                }
            }
        }
        __syncthreads();
    }
}

// ---------------- CSR build (int atomics only) ----------------
__global__ __launch_bounds__(256) void hist_kernel(
    const int* __restrict__ dst, int* __restrict__ degi, int E)
{
    const int t = blockIdx.x * 256 + threadIdx.x;
    if (t < E) atomicAdd(&degi[dst[t]], 1);
}

__global__ __launch_bounds__(256) void reduce_kernel(
    const int* __restrict__ degi, int* __restrict__ bsum, int N)
{
    const int base = blockIdx.x * 1024;
    const int t = threadIdx.x;
    int s = 0;
#pragma unroll
    for (int k = 0; k < 4; ++k){
        const int i = base + t * 4 + k;
        if (i < N) s += degi[i];
    }
    __shared__ int sh[256];
    sh[t] = s; __syncthreads();
    for (int off = 128; off > 0; off >>= 1){
        if (t < off) sh[t] += sh[t + off];
        __syncthreads();
    }
    if (t == 0) bsum[blockIdx.x] = sh[0];
}

__global__ __launch_bounds__(256) void scanb_kernel(
    const int* __restrict__ bsum, int* __restrict__ boff, int NB,
    int* __restrict__ rowptr, int N, int E)
{
    const int t = threadIdx.x;
    const int v = (t < NB) ? bsum[t] : 0;
    __shared__ int sh[256];
    sh[t] = v; __syncthreads();
    for (int off = 1; off < 256; off <<= 1){
        const int x = (t >= off) ? sh[t - off] : 0;
        __syncthreads();
        sh[t] += x;
        __syncthreads();
    }
    if (t < NB) boff[t] = sh[t] - v;
    if (t == 0) rowptr[N] = E;
}

__global__ __launch_bounds__(256) void scan_kernel(
    const int* __restrict__ degi, const int* __restrict__ boff,
    int* __restrict__ rowptr, int* __restrict__ cursor,
    float* __restrict__ degf, int N)
{
    const int base = blockIdx.x * 1024;
    const int t = threadIdx.x;
    int v[4]; int s = 0;
    const int i0 = base + t * 4;
#pragma unroll
    for (int k = 0; k < 4; ++k){
        const int i = i0 + k;
        v[k] = (i < N) ? degi[i] : 0;
        s += v[k];
    }
    __shared__ int sh[256];
    sh[t] = s; __syncthreads();
    for (int off = 1; off < 256; off <<= 1){
        const int x = (t >= off) ? sh[t - off] : 0;
        __syncthreads();
        sh[t] += x;
        __syncthreads();
    }
    int excl = sh[t] - s + boff[blockIdx.x];
#pragma unroll
    for (int k = 0; k < 4; ++k){
        const int i = i0 + k;
        if (i < N){
            rowptr[i] = excl;
            cursor[i] = excl;
            degf[i]   = (float)v[k];
            excl += v[k];
        }
    }
}

__global__ __launch_bounds__(256) void fill_kernel(
    const int* __restrict__ src, const int* __restrict__ dst,
    int* __restrict__ cursor, int* __restrict__ col, int E)
{
    const int e = blockIdx.x * 256 + threadIdx.x;
    if (e < E){
        const int p = atomicAdd(&cursor[dst[e]], 1);
        col[p] = src[e];
    }
}

// ---------------- gather aggregation (pair in / pair out) ----------------
__global__ __launch_bounds__(256) void gather_kernel(
    const u32* __restrict__ hhi, const u32* __restrict__ hlo,
    const int* __restrict__ rowptr, const int* __restrict__ col,
    u32* __restrict__ shi, u32* __restrict__ slo, int N)
{
    const int node = blockIdx.x * 4 + (threadIdx.x >> 6);
    const int lane = threadIdx.x & 63;
    if (node >= N) return;
    const int beg = rowptr[node], end = rowptr[node + 1];
    float a0 = 0.f, a1 = 0.f, b0 = 0.f, b1 = 0.f;
    int j = beg;
    for (; j + 1 < end; j += 2){
        int c0 = col[j], c1 = col[j + 1];
        u32 vh0 = hhi[(size_t)c0 * 64 + lane], vl0 = hlo[(size_t)c0 * 64 + lane];
        u32 vh1 = hhi[(size_t)c1 * 64 + lane], vl1 = hlo[(size_t)c1 * 64 + lane];
        a0 += u2f(vh0 << 16) + u2f(vl0 << 16);
        a1 += u2f(vh0 & 0xffff0000u) + u2f(vl0 & 0xffff0000u);
        b0 += u2f(vh1 << 16) + u2f(vl1 << 16);
        b1 += u2f(vh1 & 0xffff0000u) + u2f(vl1 & 0xffff0000u);
    }
    if (j < end){
        int c0 = col[j];
        u32 vh = hhi[(size_t)c0 * 64 + lane], vl = hlo[(size_t)c0 * 64 + lane];
        a0 += u2f(vh << 16) + u2f(vl << 16);
        a1 += u2f(vh & 0xffff0000u) + u2f(vl & 0xffff0000u);
    }
    a0 += b0; a1 += b1;
    u32 ho, lo; split2(a0, a1, ho, lo);
    shi[(size_t)node * 64 + lane] = ho;
    slo[(size_t)node * 64 + lane] = lo;
}

extern "C" void kernel_launch(void* const* d_in, const int* in_sizes, int n_in,
                              void* d_out, int out_size, void* d_ws, size_t ws_size,
                              hipStream_t stream)
{
    const float* NF  = (const float*)d_in[0];   // [N,256]
    const int*   EI  = (const int*)  d_in[1];   // [2,E]
    const float* Wp  = (const float*)d_in[3];   // [128,256]
    const float* bp  = (const float*)d_in[4];   // [128]
    const float* EW  = (const float*)d_in[5];   // [2,1,128,128]
    const float* EB  = (const float*)d_in[6];   // [2,1,128]
    const float* WIH = (const float*)d_in[7];   // [2,384,128]
    const float* WHH = (const float*)d_in[8];   // [2,384,128]
    const float* BIH = (const float*)d_in[9];   // [2,384]
    const float* BHH = (const float*)d_in[10];  // [2,384]
    float* out = (float*)d_out;

    const int FEAT = 256;
    const int N = in_sizes[0] / FEAT;           // 100000
    const int E = in_sizes[1] / 2;              // 640000
    const size_t NH = (size_t)N * HID;
    const int NB = (N + 1023) / 1024;

    u16* h_hi = (u16*)d_ws;
    u16* h_lo = h_hi + NH;
    u16* s_hi = h_lo + NH;
    u16* s_lo = s_hi + NH;
    float* degf = (float*)(s_lo + NH);
    u16* wp_hi  = (u16*)(degf + N);
    u16* wp_lo  = wp_hi + 32768;
    u16* whh_hi = wp_lo + 32768;    // 2 layers x 49152
    u16* whh_lo = whh_hi + 98304;
    u16* wc_hi  = whh_lo + 98304;   // 2 layers x 3 x 16384
    u16* wc_lo  = wc_hi + 98304;
    float* ebg  = (float*)(wc_lo + 98304);   // 2 x 384
    int* degi   = (int*)(ebg + 768);
    int* rowptr = degi + N;
    int* cursor = rowptr + N + 1;
    int* colA   = cursor + N;
    int* bsum   = colA + E;
    int* boff   = bsum + 256;

    // weight prep
    split_kernel<<<64, 256, 0, stream>>>(Wp, 16384, wp_hi, wp_lo);
    split_kernel<<<192, 256, 0, stream>>>(WHH, 49152, whh_hi, whh_lo);
    wcombine_kernel<<<6, 256, 0, stream>>>(WIH, EW, EB, wc_hi, wc_lo, ebg);

    // h = relu(NF @ Wp.T + bp)
    proj_kernel<<<(N + 127) / 128, 256, 0, stream>>>(NF, wp_hi, wp_lo, bp, h_hi, h_lo, N);

    // CSR of dst (shared by both layers)
    hipMemsetAsync(degi, 0, N * sizeof(int), stream);
    hist_kernel<<<(E + 255) / 256, 256, 0, stream>>>(EI + E, degi, E);
    reduce_kernel<<<NB, 256, 0, stream>>>(degi, bsum, N);
    scanb_kernel<<<1, 256, 0, stream>>>(bsum, boff, NB, rowptr, N, E);
    scan_kernel<<<NB, 256, 0, stream>>>(degi, boff, rowptr, cursor, degf, N);
    fill_kernel<<<(E + 255) / 256, 256, 0, stream>>>(EI, EI + E, cursor, colA, E);

    for (int l = 0; l < 2; ++l){
        gather_kernel<<<(N + 3) / 4, 256, 0, stream>>>(
            (const u32*)h_hi, (const u32*)h_lo, rowptr, colA,
            (u32*)s_hi, (u32*)s_lo, N);
        if (l == 0)
            gru_fused<0><<<(N + 63) / 64, 256, 0, stream>>>(
                s_hi, s_lo, h_hi, h_lo,
                wc_hi + l * 49152, wc_lo + l * 49152,
                whh_hi + l * 49152, whh_lo + l * 49152,
                ebg + l * 384, BIH + l * 384, BHH + l * 384, degf,
                h_hi, h_lo, nullptr, N);
        else
            gru_fused<1><<<(N + 63) / 64, 256, 0, stream>>>(
                s_hi, s_lo, h_hi, h_lo,
                wc_hi + l * 49152, wc_lo + l * 49152,
                whh_hi + l * 49152, whh_lo + l * 49152,
                ebg + l * 384, BIH + l * 384, BHH + l * 384, degf,
                nullptr, nullptr, out, N);
    }
}

// Round 7
// 678.531 us; speedup vs baseline: 5.1389x; 1.0805x over previous
//
#include <hip/hip_runtime.h>
#include <hip/hip_bf16.h>

// ---------------------------------------------------------------------------
// BasicGNNEncoder, MFMA bf16x3 (split hi/lo), agg-GEMM folded into GRU.
//   h = relu(NF @ Wp.T + bp)
//   Wc_g = wih_g @ We ; ebg_g = wih_g @ eb      (per layer, on device)
//   2x { s = segsum(h[src], dst) [CSR gather];
//        gates = s@Wc.T + deg*ebg + h@whh.T + biases ; h = GRU blend }
// gru_fused v4: barrier-free K-loop; A-tile staged once via global_load_lds;
// B fragments loaded from global in MFMA-FRAGMENT ORDER (coalesced 1KB
// wave-loads, L2-hot). Weights pre-permuted on device.
// Fragment layout: chunk id = (((slab*2+side)*4 + ks4)*2 + hl)*8 + nf,
// chunk = 1KB, lane l holds W[n = nf*16 + (l&15)][k = ks4*32 + (l>>4)*8 .. +8]
// ---------------------------------------------------------------------------

typedef unsigned int u32;
typedef unsigned short u16;
typedef __attribute__((ext_vector_type(8))) short bf16x8;   // 8 bf16 = 4 VGPR
typedef __attribute__((ext_vector_type(4))) float f32x4;

#define HID 128
#define WFRAG_L 196608   // u16 per layer: 384 chunks x 512

__device__ __forceinline__ float u2f(u32 b){ union{u32 u; float f;} v; v.u=b; return v.f; }
__device__ __forceinline__ u32 f2u(float f){ union{u32 u; float f;} v; v.f=f; return v.u; }

__device__ __forceinline__ void split2(float a0, float a1, u32& hi, u32& lo){
    u32 b0 = f2u(a0), b1 = f2u(a1);
    u32 h0 = b0 & 0xffff0000u, h1 = b1 & 0xffff0000u;
    hi = (b0 >> 16) | h1;
    float l0 = a0 - u2f(h0), l1 = a1 - u2f(h1);
    lo = (f2u(l0) >> 16) | (f2u(l1) & 0xffff0000u);
}

__device__ __forceinline__ float sigm(float x){ return 1.f / (1.f + __expf(-x)); }
__device__ __forceinline__ float tanh_f(float x){ return 1.f - 2.f / (1.f + __expf(2.f * x)); }

__device__ __forceinline__ void gload16(const u16* g, u16* l){
    __builtin_amdgcn_global_load_lds(
        (const __attribute__((address_space(1))) u32*)g,
        (__attribute__((address_space(3))) u32*)l, 16, 0, 0);
}

// ---------------- weight split prep (proj weights, row-major) --------------
__global__ __launch_bounds__(256) void split_kernel(
    const float* __restrict__ src, int npairs, u16* __restrict__ hi, u16* __restrict__ lo)
{
    int i = blockIdx.x * 256 + threadIdx.x;
    if (i < npairs){
        float2 a = ((const float2*)src)[i];
        u32 h, l; split2(a.x, a.y, h, l);
        ((u32*)hi)[i] = h; ((u32*)lo)[i] = l;
    }
}

// ---------------- whh -> fragment-order split ------------------------------
__global__ __launch_bounds__(256) void fragsplit_whh(
    const float* __restrict__ WHH, u16* __restrict__ wfrag)
{
    int i = blockIdx.x * 256 + threadIdx.x;          // pair index
    if (i >= 2 * 384 * 64) return;
    const int l   = i / (384 * 64);
    const int rem = i % (384 * 64);
    const int row = rem >> 6;          // g*128 + n
    const int kp  = (rem & 63) * 2;    // even k
    const int g = row >> 7, n = row & 127;
    float2 a = *(const float2*)&WHH[((size_t)l * 384 + row) * 128 + kp];
    u32 hb, lb; split2(a.x, a.y, hb, lb);
    const int ch   = (((g * 2 + 1) * 4 + (kp >> 5)) * 2 + 0) * 8 + (n >> 4);
    const int widx = (((kp >> 3) & 3) * 16 + (n & 15)) * 4 + ((kp & 7) >> 1);
    u32* dst = (u32*)(wfrag + (size_t)l * WFRAG_L);
    dst[ch * 256 + widx]       = hb;
    dst[(ch + 8) * 256 + widx] = lb;
}

// ---------------- Wc = wih_g @ We (fragment-order out), ebg = wih_g @ eb ---
__global__ __launch_bounds__(256) void wcombine_kernel(
    const float* __restrict__ WIH, const float* __restrict__ EW,
    const float* __restrict__ EB,
    u16* __restrict__ wfrag, float* __restrict__ ebg)
{
    __shared__ float WeL[16384];
    const int l = blockIdx.x / 3, g = blockIdx.x % 3;
    const int t = threadIdx.x;
    for (int u = t; u < 4096; u += 256)
        ((float4*)WeL)[u] = ((const float4*)(EW + (size_t)l * 16384))[u];
    __syncthreads();

    const int r = t >> 1, jh = (t & 1) * 64;     // r = out row n, jh = k base
    const float* wr = WIH + ((size_t)l * 384 + g * 128 + r) * 128;
    float a[64];
#pragma unroll
    for (int j = 0; j < 64; ++j) a[j] = 0.f;
    for (int k = 0; k < 128; ++k){
        const float wv = wr[k];
        const float4* wel = (const float4*)(WeL + k * 128 + jh);
#pragma unroll
        for (int jj = 0; jj < 16; ++jj){
            float4 v = wel[jj];
            a[jj*4+0] = fmaf(wv, v.x, a[jj*4+0]);
            a[jj*4+1] = fmaf(wv, v.y, a[jj*4+1]);
            a[jj*4+2] = fmaf(wv, v.z, a[jj*4+2]);
            a[jj*4+3] = fmaf(wv, v.w, a[jj*4+3]);
        }
    }
    u32* dst = (u32*)(wfrag + (size_t)l * WFRAG_L);
#pragma unroll
    for (int j = 0; j < 64; j += 2){
        u32 hb, lb; split2(a[j], a[j+1], hb, lb);
        const int k0 = jh + j;
        const int ch   = (((g * 2 + 0) * 4 + (k0 >> 5)) * 2 + 0) * 8 + (r >> 4);
        const int widx = (((k0 >> 3) & 3) * 16 + (r & 15)) * 4 + ((k0 & 7) >> 1);
        dst[ch * 256 + widx]       = hb;
        dst[(ch + 8) * 256 + widx] = lb;
    }
    if (t < 128){
        const float* wr2 = WIH + ((size_t)l * 384 + g * 128 + t) * 128;
        const float* eb = EB + (size_t)l * 128;
        float s = 0.f;
        for (int k = 0; k < 128; ++k) s = fmaf(wr2[k], eb[k], s);
        ebg[(l * 3 + g) * 128 + t] = s;
    }
}

// ---------------- proj: h = relu(NF @ Wp.T + bp), pair out -----------------
__global__ __launch_bounds__(256) void proj_kernel(
    const float* __restrict__ A,
    const u16* __restrict__ Whi, const u16* __restrict__ Wlo,   // [128][256] split
    const float* __restrict__ bias,
    u16* __restrict__ Ohi, u16* __restrict__ Olo, int M)
{
    constexpr int K = 256;
    __shared__ __align__(16) u16 ldsB[8192];   // [hl][kg4][row128][8] = 16KB
    const int tid = threadIdx.x, lane = tid & 63, w = tid >> 6;
    const int m0 = blockIdx.x * 128;

    f32x4 acc[2][8];
#pragma unroll
    for (int a = 0; a < 2; ++a)
#pragma unroll
        for (int b = 0; b < 8; ++b) acc[a][b] = (f32x4){0.f, 0.f, 0.f, 0.f};

    for (int ks = 0; ks < K / 32; ++ks){
        for (int u = tid; u < 1024; u += 256){
            int flat = u * 8;
            int hl = flat >> 12, rem = flat & 4095;
            int kg = rem >> 10, row = (rem >> 3) & 127;
            const u16* srcp = hl ? Wlo : Whi;
            bf16x8 v = *(const bf16x8*)&srcp[row * K + ks * 32 + kg * 8];
            *(bf16x8*)&ldsB[flat] = v;
        }
        __syncthreads();

        bf16x8 ah[2], al[2];
#pragma unroll
        for (int mf = 0; mf < 2; ++mf){
            int row = m0 + w * 32 + mf * 16 + (lane & 15);
            row = row < M ? row : M - 1;
            const float* ap = A + (size_t)row * K + ks * 32 + (lane >> 4) * 8;
            float4 fa = *(const float4*)ap;
            float4 fb = *(const float4*)(ap + 4);
            union{ bf16x8 v; u32 u[4]; } H, L;
            split2(fa.x, fa.y, H.u[0], L.u[0]);
            split2(fa.z, fa.w, H.u[1], L.u[1]);
            split2(fb.x, fb.y, H.u[2], L.u[2]);
            split2(fb.z, fb.w, H.u[3], L.u[3]);
            ah[mf] = H.v; al[mf] = L.v;
        }
#pragma unroll
        for (int nf = 0; nf < 8; ++nf){
            int bi = (lane >> 4) * 1024 + (nf * 16 + (lane & 15)) * 8;
            bf16x8 bh = *(const bf16x8*)&ldsB[bi];
            bf16x8 bl = *(const bf16x8*)&ldsB[bi + 4096];
#pragma unroll
            for (int mf = 0; mf < 2; ++mf){
                acc[mf][nf] = __builtin_amdgcn_mfma_f32_16x16x32_bf16(ah[mf], bh, acc[mf][nf], 0, 0, 0);
                acc[mf][nf] = __builtin_amdgcn_mfma_f32_16x16x32_bf16(ah[mf], bl, acc[mf][nf], 0, 0, 0);
                acc[mf][nf] = __builtin_amdgcn_mfma_f32_16x16x32_bf16(al[mf], bh, acc[mf][nf], 0, 0, 0);
            }
        }
        __syncthreads();
    }
#pragma unroll
    for (int mf = 0; mf < 2; ++mf)
#pragma unroll
        for (int nf = 0; nf < 8; ++nf){
            int col = nf * 16 + (lane & 15);
#pragma unroll
            for (int r = 0; r < 4; ++r){
                int grow = m0 + w * 32 + mf * 16 + (lane >> 4) * 4 + r;
                if (grow < M){
                    float v = acc[mf][nf][r] + bias[col];
                    v = fmaxf(v, 0.f);
                    u32 b = f2u(v);
                    float lv = v - u2f(b & 0xffff0000u);
                    size_t o = (size_t)grow * HID + col;
                    Ohi[o] = (u16)(b >> 16);
                    Olo[o] = (u16)(f2u(lv) >> 16);
                }
            }
        }
}

// ---------------- fused GRU v4: frag-ordered B, barrier-free K-loop --------
// Block 256 thr = 4 waves, BM=64 rows. plane = (w + blockIdx) & 3:
//   plane0: R (K=256: s@WcR then h@whhR); plane1: Z; plane2: I (s only);
//   plane3: H (h only). slab = min(plane,2); side = (ks<4) ? 0 : 1.
template<int LAST>
__global__ __launch_bounds__(256, 2) void gru_fused(
    const u16* __restrict__ s_hi,  const u16* __restrict__ s_lo,
    const u16* __restrict__ h_hi,  const u16* __restrict__ h_lo,
    const u16* __restrict__ Wf,                                      // frag-order
    const float* __restrict__ ebg,                                   // [3][128]
    const float* __restrict__ bih, const float* __restrict__ bhh,    // [384]
    const float* __restrict__ degf,
    u16* __restrict__ out_hi, u16* __restrict__ out_lo, float* __restrict__ outf,
    int M)
{
    __shared__ __align__(16) u16 lds[32768];     // 64KB A-tile / epilogue planes
    const int tid = threadIdx.x, lane = tid & 63, w = tid >> 6;
    const int m0 = blockIdx.x * 64;
    const int plane = (w + blockIdx.x) & 3;
    const int slab = (plane < 2) ? plane : 2;

    // ---- stage A tile once: 64 chunks x 1KB (lane = row) ----
    {
        int gr = m0 + lane; gr = gr < M ? gr : M - 1;
        const size_t ro = (size_t)gr * HID;
#pragma unroll
        for (int i = 0; i < 16; ++i){
            const int c = w * 16 + i;
            const int side = c >> 5, hl = (c >> 4) & 1, kg = c & 15;
            const u16* base = side ? (hl ? h_lo : h_hi) : (hl ? s_lo : s_hi);
            gload16(base + ro + kg * 8, &lds[c * 512 + lane * 8]);
        }
    }
    __syncthreads();

    f32x4 acc[4][8];
#pragma unroll
    for (int a = 0; a < 4; ++a)
#pragma unroll
        for (int b = 0; b < 8; ++b) acc[a][b] = (f32x4){0.f,0.f,0.f,0.f};

    const int lof = lane * 8;

    // ---- barrier-free K loop ----
    for (int ks = 0; ks < 8; ++ks){
        const bool sside = ks < 4;
        const bool active = (plane < 2) || ((plane == 2) == sside);
        if (!active) continue;

        // chunk base for this (slab, side, ks4), hl=0
        const int cb = ((slab * 2 + (sside ? 0 : 1)) * 4 + (ks & 3)) * 16;

        // A frags from LDS (conflict-free: 16B stride across lanes)
        const int abase = (sside ? 0 : 16384) + ((ks & 3) * 4 + (lane >> 4)) * 512
                        + (lane & 15) * 8;
        bf16x8 ah[4], al[4];
#pragma unroll
        for (int mf = 0; mf < 4; ++mf){
            ah[mf] = *(const bf16x8*)&lds[abase + mf * 128];
            al[mf] = *(const bf16x8*)&lds[abase + mf * 128 + 8192];
        }

#pragma unroll
        for (int nf = 0; nf < 8; ++nf){
            bf16x8 bh = *(const bf16x8*)&Wf[(cb + nf) * 512 + lof];
            bf16x8 bl = *(const bf16x8*)&Wf[(cb + 8 + nf) * 512 + lof];
#pragma unroll
            for (int mf = 0; mf < 4; ++mf){
                acc[mf][nf] = __builtin_amdgcn_mfma_f32_16x16x32_bf16(ah[mf], bh, acc[mf][nf], 0, 0, 0);
                acc[mf][nf] = __builtin_amdgcn_mfma_f32_16x16x32_bf16(ah[mf], bl, acc[mf][nf], 0, 0, 0);
                acc[mf][nf] = __builtin_amdgcn_mfma_f32_16x16x32_bf16(al[mf], bh, acc[mf][nf], 0, 0, 0);
            }
        }
    }

    __syncthreads();    // A-tile reads done; lds becomes plane-exchange buffer

    // ---- epilogue: exchange planes via padded LDS, 16-row quarters ----
    float* planes = (float*)lds;         // [4 planes][16][132] f32
#pragma unroll 4
    for (int q = 0; q < 4; ++q){
#pragma unroll
        for (int nf = 0; nf < 8; ++nf){
#pragma unroll
            for (int r = 0; r < 4; ++r){
                const int row16 = (lane >> 4) * 4 + r;
                const int col = nf * 16 + (lane & 15);
                planes[plane * 2112 + row16 * 132 + col] = acc[q][nf][r];
            }
        }
        __syncthreads();
        {
            const int row16 = tid >> 4;
            const int c0 = (tid & 15) * 8;
            const int gr = m0 + q * 16 + row16;
            if (gr < M){
                const float dgv = degf[gr];
                const size_t base = (size_t)gr * HID + c0;
                const int sw = row16 * 132 + c0;
                union{ bf16x8 v; u16 e[8]; } Hh, Hl;
                Hh.v = *(const bf16x8*)&h_hi[base];
                Hl.v = *(const bf16x8*)&h_lo[base];
                float o[8];
#pragma unroll
                for (int j = 0; j < 8; ++j){
                    const int c = c0 + j;
                    const float R  = planes[sw + j];
                    const float Z  = planes[2112 + sw + j];
                    const float NI = planes[4224 + sw + j];
                    const float NH = planes[6336 + sw + j];
                    const float rg = sigm(R + dgv * ebg[c] + bih[c] + bhh[c]);
                    const float zg = sigm(Z + dgv * ebg[128 + c] + bih[128 + c] + bhh[128 + c]);
                    const float hv = u2f((u32)Hh.e[j] << 16) + u2f((u32)Hl.e[j] << 16);
                    const float nn = tanh_f(NI + dgv * ebg[256 + c] + bih[256 + c]
                                            + rg * (NH + bhh[256 + c]));
                    o[j] = nn + zg * (hv - nn);
                }
                if (LAST){
                    *(float4*)&outf[base]     = make_float4(o[0], o[1], o[2], o[3]);
                    *(float4*)&outf[base + 4] = make_float4(o[4], o[5], o[6], o[7]);
                } else {
#pragma unroll
                    for (int j = 0; j < 4; ++j){
                        u32 hb, lb; split2(o[2*j], o[2*j+1], hb, lb);
                        ((u32*)out_hi)[(base >> 1) + j] = hb;
                        ((u32*)out_lo)[(base >> 1) + j] = lb;
                    }
                }
            }
        }
        __syncthreads();
    }
}

// ---------------- CSR build (int atomics only) ----------------
__global__ __launch_bounds__(256) void hist_kernel(
    const int* __restrict__ dst, int* __restrict__ degi, int E)
{
    const int t = blockIdx.x * 256 + threadIdx.x;
    if (t < E) atomicAdd(&degi[dst[t]], 1);
}

__global__ __launch_bounds__(256) void reduce_kernel(
    const int* __restrict__ degi, int* __restrict__ bsum, int N)
{
    const int base = blockIdx.x * 1024;
    const int t = threadIdx.x;
    int s = 0;
#pragma unroll
    for (int k = 0; k < 4; ++k){
        const int i = base + t * 4 + k;
        if (i < N) s += degi[i];
    }
    __shared__ int sh[256];
    sh[t] = s; __syncthreads();
    for (int off = 128; off > 0; off >>= 1){
        if (t < off) sh[t] += sh[t + off];
        __syncthreads();
    }
    if (t == 0) bsum[blockIdx.x] = sh[0];
}

__global__ __launch_bounds__(256) void scanb_kernel(
    const int* __restrict__ bsum, int* __restrict__ boff, int NB,
    int* __restrict__ rowptr, int N, int E)
{
    const int t = threadIdx.x;
    const int v = (t < NB) ? bsum[t] : 0;
    __shared__ int sh[256];
    sh[t] = v; __syncthreads();
    for (int off = 1; off < 256; off <<= 1){
        const int x = (t >= off) ? sh[t - off] : 0;
        __syncthreads();
        sh[t] += x;
        __syncthreads();
    }
    if (t < NB) boff[t] = sh[t] - v;
    if (t == 0) rowptr[N] = E;
}

__global__ __launch_bounds__(256) void scan_kernel(
    const int* __restrict__ degi, const int* __restrict__ boff,
    int* __restrict__ rowptr, int* __restrict__ cursor,
    float* __restrict__ degf, int N)
{
    const int base = blockIdx.x * 1024;
    const int t = threadIdx.x;
    int v[4]; int s = 0;
    const int i0 = base + t * 4;
#pragma unroll
    for (int k = 0; k < 4; ++k){
        const int i = i0 + k;
        v[k] = (i < N) ? degi[i] : 0;
        s += v[k];
    }
    __shared__ int sh[256];
    sh[t] = s; __syncthreads();
    for (int off = 1; off < 256; off <<= 1){
        const int x = (t >= off) ? sh[t - off] : 0;
        __syncthreads();
        sh[t] += x;
        __syncthreads();
    }
    int excl = sh[t] - s + boff[blockIdx.x];
#pragma unroll
    for (int k = 0; k < 4; ++k){
        const int i = i0 + k;
        if (i < N){
            rowptr[i] = excl;
            cursor[i] = excl;
            degf[i]   = (float)v[k];
            excl += v[k];
        }
    }
}

__global__ __launch_bounds__(256) void fill_kernel(
    const int* __restrict__ src, const int* __restrict__ dst,
    int* __restrict__ cursor, int* __restrict__ col, int E)
{
    const int e = blockIdx.x * 256 + threadIdx.x;
    if (e < E){
        const int p = atomicAdd(&cursor[dst[e]], 1);
        col[p] = src[e];
    }
}

// ---------------- gather aggregation (pair in / pair out) ----------------
__global__ __launch_bounds__(256) void gather_kernel(
    const u32* __restrict__ hhi, const u32* __restrict__ hlo,
    const int* __restrict__ rowptr, const int* __restrict__ col,
    u32* __restrict__ shi, u32* __restrict__ slo, int N)
{
    const int node = blockIdx.x * 4 + (threadIdx.x >> 6);
    const int lane = threadIdx.x & 63;
    if (node >= N) return;
    const int beg = rowptr[node], end = rowptr[node + 1];
    float a0 = 0.f, a1 = 0.f, b0 = 0.f, b1 = 0.f;
    int j = beg;
    for (; j + 1 < end; j += 2){
        int c0 = col[j], c1 = col[j + 1];
        u32 vh0 = hhi[(size_t)c0 * 64 + lane], vl0 = hlo[(size_t)c0 * 64 + lane];
        u32 vh1 = hhi[(size_t)c1 * 64 + lane], vl1 = hlo[(size_t)c1 * 64 + lane];
        a0 += u2f(vh0 << 16) + u2f(vl0 << 16);
        a1 += u2f(vh0 & 0xffff0000u) + u2f(vl0 & 0xffff0000u);
        b0 += u2f(vh1 << 16) + u2f(vl1 << 16);
        b1 += u2f(vh1 & 0xffff0000u) + u2f(vl1 & 0xffff0000u);
    }
    if (j < end){
        int c0 = col[j];
        u32 vh = hhi[(size_t)c0 * 64 + lane], vl = hlo[(size_t)c0 * 64 + lane];
        a0 += u2f(vh << 16) + u2f(vl << 16);
        a1 += u2f(vh & 0xffff0000u) + u2f(vl & 0xffff0000u);
    }
    a0 += b0; a1 += b1;
    u32 ho, lo; split2(a0, a1, ho, lo);
    shi[(size_t)node * 64 + lane] = ho;
    slo[(size_t)node * 64 + lane] = lo;
}

extern "C" void kernel_launch(void* const* d_in, const int* in_sizes, int n_in,
                              void* d_out, int out_size, void* d_ws, size_t ws_size,
                              hipStream_t stream)
{
    const float* NF  = (const float*)d_in[0];   // [N,256]
    const int*   EI  = (const int*)  d_in[1];   // [2,E]
    const float* Wp  = (const float*)d_in[3];   // [128,256]
    const float* bp  = (const float*)d_in[4];   // [128]
    const float* EW  = (const float*)d_in[5];   // [2,1,128,128]
    const float* EB  = (const float*)d_in[6];   // [2,1,128]
    const float* WIH = (const float*)d_in[7];   // [2,384,128]
    const float* WHH = (const float*)d_in[8];   // [2,384,128]
    const float* BIH = (const float*)d_in[9];   // [2,384]
    const float* BHH = (const float*)d_in[10];  // [2,384]
    float* out = (float*)d_out;

    const int FEAT = 256;
    const int N = in_sizes[0] / FEAT;           // 100000
    const int E = in_sizes[1] / 2;              // 640000
    const size_t NH = (size_t)N * HID;
    const int NB = (N + 1023) / 1024;

    u16* h_hi = (u16*)d_ws;
    u16* h_lo = h_hi + NH;
    u16* s_hi = h_lo + NH;
    u16* s_lo = s_hi + NH;
    float* degf = (float*)(s_lo + NH);
    u16* wp_hi  = (u16*)(degf + N);
    u16* wp_lo  = wp_hi + 32768;
    u16* wfrag  = wp_lo + 32768;             // 2 layers x 196608 u16 (frag order)
    float* ebg  = (float*)(wfrag + 2 * WFRAG_L);   // 2 x 384
    int* degi   = (int*)(ebg + 768);
    int* rowptr = degi + N;
    int* cursor = rowptr + N + 1;
    int* colA   = cursor + N;
    int* bsum   = colA + E;
    int* boff   = bsum + 256;

    // weight prep
    split_kernel<<<64, 256, 0, stream>>>(Wp, 16384, wp_hi, wp_lo);
    fragsplit_whh<<<192, 256, 0, stream>>>(WHH, wfrag);
    wcombine_kernel<<<6, 256, 0, stream>>>(WIH, EW, EB, wfrag, ebg);

    // h = relu(NF @ Wp.T + bp)
    proj_kernel<<<(N + 127) / 128, 256, 0, stream>>>(NF, wp_hi, wp_lo, bp, h_hi, h_lo, N);

    // CSR of dst (shared by both layers)
    hipMemsetAsync(degi, 0, N * sizeof(int), stream);
    hist_kernel<<<(E + 255) / 256, 256, 0, stream>>>(EI + E, degi, E);
    reduce_kernel<<<NB, 256, 0, stream>>>(degi, bsum, N);
    scanb_kernel<<<1, 256, 0, stream>>>(bsum, boff, NB, rowptr, N, E);
    scan_kernel<<<NB, 256, 0, stream>>>(degi, boff, rowptr, cursor, degf, N);
    fill_kernel<<<(E + 255) / 256, 256, 0, stream>>>(EI, EI + E, cursor, colA, E);

    for (int l = 0; l < 2; ++l){
        gather_kernel<<<(N + 3) / 4, 256, 0, stream>>>(
            (const u32*)h_hi, (const u32*)h_lo, rowptr, colA,
            (u32*)s_hi, (u32*)s_lo, N);
        if (l == 0)
            gru_fused<0><<<(N + 63) / 64, 256, 0, stream>>>(
                s_hi, s_lo, h_hi, h_lo,
                wfrag + (size_t)l * WFRAG_L,
                ebg + l * 384, BIH + l * 384, BHH + l * 384, degf,
                h_hi, h_lo, nullptr, N);
        else
            gru_fused<1><<<(N + 63) / 64, 256, 0, stream>>>(
                s_hi, s_lo, h_hi, h_lo,
                wfrag + (size_t)l * WFRAG_L,
                ebg + l * 384, BIH + l * 384, BHH + l * 384, degf,
                nullptr, nullptr, out, N);
    }
}